// Round 1
// baseline (2370.597 us; speedup 1.0000x reference)
//
#include <hip/hip_runtime.h>

#define NN 50000
#define HH 128
#define CC 16
#define RRL 8
#define BB 4
#define EE 800000

// ---------------- bucketing edges by relation (counting sort) ----------------

__global__ void zero_cnt_kernel(int* cnt, int* cur) {
  int t = threadIdx.x;
  if (t < RRL) { cnt[t] = 0; cur[t] = 0; }
}

__global__ __launch_bounds__(256) void hist_kernel(const int* __restrict__ r,
                                                   int* __restrict__ cnt) {
  __shared__ int hc[RRL];
  int t = threadIdx.x;
  if (t < RRL) hc[t] = 0;
  __syncthreads();
  int e = blockIdx.x * 256 + t;
  if (e < EE) atomicAdd(&hc[r[e]], 1);
  __syncthreads();
  if (t < RRL) atomicAdd(&cnt[t], hc[t]);
}

__global__ void scan_kernel(const int* cnt, int* off, int* cur) {
  if (threadIdx.x == 0) {
    int a = 0;
    for (int i = 0; i < RRL; ++i) { off[i] = a; cur[i] = a; a += cnt[i]; }
    off[RRL] = a;
  }
}

__global__ __launch_bounds__(256) void scatter_kernel(const int* __restrict__ r,
                                                      int* __restrict__ cur,
                                                      int* __restrict__ perm) {
  __shared__ int hc[RRL], base[RRL];
  int t = threadIdx.x;
  if (t < RRL) hc[t] = 0;
  __syncthreads();
  int e = blockIdx.x * 256 + t;
  int rr = 0, lpos = 0;
  bool valid = (e < EE);
  if (valid) { rr = r[e]; lpos = atomicAdd(&hc[rr], 1); }
  __syncthreads();
  if (t < RRL) base[t] = atomicAdd(&cur[t], hc[t]);
  __syncthreads();
  if (valid) perm[base[rr] + lpos] = e;
}

// ---------------- compose w1 = wcomp1@bases1, w2 = wcomp2@bases2 ----------------

__global__ __launch_bounds__(256) void compose_w_kernel(
    const float* __restrict__ wcomp1, const float* __restrict__ bases1,
    const float* __restrict__ wcomp2, const float* __restrict__ bases2,
    float* __restrict__ w1, float* __restrict__ w2) {
  int idx = blockIdx.x * 256 + threadIdx.x;
  if (idx < RRL * HH * HH) {
    int rr = idx / (HH * HH);
    int rem = idx - rr * HH * HH;
    float a = 0.f;
#pragma unroll
    for (int b = 0; b < BB; ++b) a += wcomp1[rr * BB + b] * bases1[b * HH * HH + rem];
    w1[idx] = a;
  } else {
    int j = idx - RRL * HH * HH;  // < RRL*HH*CC
    int rr = j / (HH * CC);
    int rem = j - rr * HH * CC;
    float a = 0.f;
#pragma unroll
    for (int b = 0; b < BB; ++b) a += wcomp2[rr * BB + b] * bases2[b * HH * CC + rem];
    w2[j] = a;
  }
}

// ---------------- layer 0 ----------------

// x1[n,f] = loop0[h[n],f] + bias0[f]   (pre-relu accumulator init)
__global__ __launch_bounds__(256) void l0_init_kernel(const int* __restrict__ h,
                                                      const float* __restrict__ loop0,
                                                      const float* __restrict__ bias0,
                                                      float* __restrict__ x1) {
  int idx = blockIdx.x * 256 + threadIdx.x;  // float4 index
  int n = idx >> 5;                          // 32 float4 per row
  int f4 = idx & 31;
  if (n >= NN) return;
  int hn = h[n];
  float4 lv = ((const float4*)(loop0 + (size_t)hn * HH))[f4];
  float4 bv = ((const float4*)bias0)[f4];
  float4 o;
  o.x = lv.x + bv.x; o.y = lv.y + bv.y; o.z = lv.z + bv.z; o.w = lv.w + bv.w;
  ((float4*)(x1 + (size_t)n * HH))[f4] = o;
}

// one wave per edge: msg = norm * sum_b wcomp0[r,b]*bases0[b, h[src], :]; atomic into x1[dst]
__global__ __launch_bounds__(256) void l0_edges_kernel(
    const int* __restrict__ src, const int* __restrict__ dst, const int* __restrict__ h,
    const int* __restrict__ r, const float* __restrict__ norm,
    const float* __restrict__ wcomp0, const float* __restrict__ bases0,
    float* __restrict__ x1) {
  int lane = threadIdx.x & 63;
  int wid = blockIdx.x * 4 + (threadIdx.x >> 6);
  int nw = gridDim.x * 4;
  for (int e = wid; e < EE; e += nw) {
    int s = h[src[e]];
    int d = dst[e];
    int rr = r[e];
    float nrm = norm[e];
    float c0 = nrm * wcomp0[rr * BB + 0];
    float c1 = nrm * wcomp0[rr * BB + 1];
    float c2 = nrm * wcomp0[rr * BB + 2];
    float c3 = nrm * wcomp0[rr * BB + 3];
    const float2* p0 = (const float2*)(bases0 + ((size_t)(0 * NN + s)) * HH);
    const float2* p1 = (const float2*)(bases0 + ((size_t)(1 * NN + s)) * HH);
    const float2* p2 = (const float2*)(bases0 + ((size_t)(2 * NN + s)) * HH);
    const float2* p3 = (const float2*)(bases0 + ((size_t)(3 * NN + s)) * HH);
    float2 v0 = p0[lane], v1 = p1[lane], v2 = p2[lane], v3 = p3[lane];
    float ox = c0 * v0.x + c1 * v1.x + c2 * v2.x + c3 * v3.x;
    float oy = c0 * v0.y + c1 * v1.y + c2 * v2.y + c3 * v3.y;
    float* o = x1 + (size_t)d * HH + lane * 2;
    atomicAdd(o, ox);
    atomicAdd(o + 1, oy);
  }
}

// ---------------- fp32 GEMM: out[z] = (relu?)A @ W[z] (+bias), A:[M,128], W:[128,F] ----------------

template <int F, bool BIAS, bool RELU_A>
__global__ __launch_bounds__(256) void gemm_kernel(const float* __restrict__ A,
                                                   const float* __restrict__ W,
                                                   const float* __restrict__ bias,
                                                   float* __restrict__ out, int M) {
  constexpr int K = HH;
  constexpr int KB = 64;
  constexpr int TM = 64;
  constexpr int WP = (F == 128) ? 132 : 20;  // 16B-aligned row strides
  const int z = blockIdx.y;
  const float* Wz = W + (size_t)z * K * F;
  float* outz = out + (size_t)z * M * F;
  const int row0 = blockIdx.x * TM;
  const int tid = threadIdx.x;

  __shared__ float xs[KB][TM + 4];  // transposed A tile: xs[k][row]
  __shared__ float ws[KB][WP];

  float acc[4][(F == 128) ? 8 : 1];
#pragma unroll
  for (int i = 0; i < 4; ++i)
#pragma unroll
    for (int j = 0; j < ((F == 128) ? 8 : 1); ++j) acc[i][j] = 0.f;
  float acc16[4] = {0.f, 0.f, 0.f, 0.f};  // used by F==16 path

  for (int kb = 0; kb < K / KB; ++kb) {
    if (kb) __syncthreads();
    // A tile: TM rows x KB k, scalar coalesced loads, transpose into LDS
#pragma unroll
    for (int i = 0; i < TM * KB / 256; ++i) {
      int flat = tid + i * 256;
      int rrow = flat >> 6;
      int kk = flat & 63;
      int g = row0 + rrow;
      float v = (g < M) ? A[(size_t)g * K + kb * KB + kk] : 0.f;
      if (RELU_A) v = fmaxf(v, 0.f);
      xs[kk][rrow] = v;
    }
    // W tile: KB x F
#pragma unroll
    for (int i = 0; i < KB * F / 256; ++i) {
      int flat = tid + i * 256;
      int kk = flat / F;
      int ff = flat - kk * F;
      ws[kk][ff] = Wz[(size_t)(kb * KB + kk) * F + ff];
    }
    __syncthreads();

    if constexpr (F == 128) {
      const int r0 = (tid & 15) * 4;
      const int c0 = (tid >> 4) * 8;
#pragma unroll 4
      for (int k = 0; k < KB; ++k) {
        float4 xv = *(const float4*)&xs[k][r0];
        float4 wa = *(const float4*)&ws[k][c0];
        float4 wb = *(const float4*)&ws[k][c0 + 4];
        float xr[4] = {xv.x, xv.y, xv.z, xv.w};
        float wc[8] = {wa.x, wa.y, wa.z, wa.w, wb.x, wb.y, wb.z, wb.w};
#pragma unroll
        for (int i = 0; i < 4; ++i)
#pragma unroll
          for (int j = 0; j < 8; ++j) acc[i][j] = fmaf(xr[i], wc[j], acc[i][j]);
      }
    } else {
      const int rrow = tid >> 2;
      const int c0 = (tid & 3) * 4;
#pragma unroll 4
      for (int k = 0; k < KB; ++k) {
        float xv = xs[k][rrow];
        float4 wv = *(const float4*)&ws[k][c0];
        acc16[0] = fmaf(xv, wv.x, acc16[0]);
        acc16[1] = fmaf(xv, wv.y, acc16[1]);
        acc16[2] = fmaf(xv, wv.z, acc16[2]);
        acc16[3] = fmaf(xv, wv.w, acc16[3]);
      }
    }
  }

  if constexpr (F == 128) {
    const int r0 = (tid & 15) * 4;
    const int c0 = (tid >> 4) * 8;
    float4 b0 = make_float4(0.f, 0.f, 0.f, 0.f), b1 = b0;
    if (BIAS) {
      b0 = *(const float4*)&bias[c0];
      b1 = *(const float4*)&bias[c0 + 4];
    }
#pragma unroll
    for (int i = 0; i < 4; ++i) {
      int g = row0 + r0 + i;
      if (g >= M) continue;
      float4 o0, o1;
      o0.x = acc[i][0] + b0.x; o0.y = acc[i][1] + b0.y;
      o0.z = acc[i][2] + b0.z; o0.w = acc[i][3] + b0.w;
      o1.x = acc[i][4] + b1.x; o1.y = acc[i][5] + b1.y;
      o1.z = acc[i][6] + b1.z; o1.w = acc[i][7] + b1.w;
      *(float4*)&outz[(size_t)g * F + c0] = o0;
      *(float4*)&outz[(size_t)g * F + c0 + 4] = o1;
    }
  } else {
    const int rrow = tid >> 2;
    const int c0 = (tid & 3) * 4;
    int g = row0 + rrow;
    if (g < M) {
      float4 bv = make_float4(0.f, 0.f, 0.f, 0.f);
      if (BIAS) bv = *(const float4*)&bias[c0];
      float4 o;
      o.x = acc16[0] + bv.x; o.y = acc16[1] + bv.y;
      o.z = acc16[2] + bv.z; o.w = acc16[3] + bv.w;
      *(float4*)&outz[(size_t)g * F + c0] = o;
    }
  }
}

// ---------------- layer 1 gather: x2[dst] += norm * trans[src] (one relation) ----------------

__global__ __launch_bounds__(256) void l1_gather_kernel(
    const int* __restrict__ src, const int* __restrict__ dst,
    const float* __restrict__ norm, const int* __restrict__ perm,
    const int* __restrict__ off, int rel, const float* __restrict__ trans,
    float* __restrict__ x2) {
  int base = off[rel];
  int bsz = off[rel + 1] - base;
  int lane = threadIdx.x & 63;
  int wid = blockIdx.x * 4 + (threadIdx.x >> 6);
  int nw = gridDim.x * 4;
  for (int i = wid; i < bsz; i += nw) {
    int e = perm[base + i];
    int s = src[e];
    int d = dst[e];
    float nrm = norm[e];
    float2 tv = *(const float2*)(trans + (size_t)s * HH + lane * 2);
    float* o = x2 + (size_t)d * HH + lane * 2;
    atomicAdd(o, tv.x * nrm);
    atomicAdd(o + 1, tv.y * nrm);
  }
}

// ---------------- layer 2 gather: out[dst] += norm * trans2[r, src] ----------------

__global__ __launch_bounds__(256) void l2_gather_kernel(
    const int* __restrict__ src, const int* __restrict__ dst, const int* __restrict__ r,
    const float* __restrict__ norm, const float* __restrict__ trans2,
    float* __restrict__ outp) {
  int lane16 = threadIdx.x & 15;
  int gid = (blockIdx.x * 256 + threadIdx.x) >> 4;
  int stride = (gridDim.x * 256) >> 4;
  for (int e = gid; e < EE; e += stride) {
    int s = src[e];
    int d = dst[e];
    int rr = r[e];
    float nrm = norm[e];
    float v = trans2[((size_t)rr * NN + s) * CC + lane16] * nrm;
    atomicAdd(outp + (size_t)d * CC + lane16, v);
  }
}

// ---------------- launch ----------------

extern "C" void kernel_launch(void* const* d_in, const int* in_sizes, int n_in,
                              void* d_out, int out_size, void* d_ws, size_t ws_size,
                              hipStream_t stream) {
  const int* src = (const int*)d_in[0];
  const int* dst = (const int*)d_in[1];
  const int* h = (const int*)d_in[2];
  const int* r = (const int*)d_in[3];
  const float* norm = (const float*)d_in[4];
  const float* bases0 = (const float*)d_in[5];
  const float* wcomp0 = (const float*)d_in[6];
  const float* loop0 = (const float*)d_in[7];
  const float* bias0 = (const float*)d_in[8];
  const float* bases1 = (const float*)d_in[9];
  const float* wcomp1 = (const float*)d_in[10];
  const float* loop1 = (const float*)d_in[11];
  const float* bias1 = (const float*)d_in[12];
  const float* bases2 = (const float*)d_in[13];
  const float* wcomp2 = (const float*)d_in[14];
  const float* loop2 = (const float*)d_in[15];
  const float* bias2 = (const float*)d_in[16];
  float* out = (float*)d_out;

  float* ws = (float*)d_ws;
  float* x1 = ws;                                    // N*H
  float* x2 = x1 + (size_t)NN * HH;                  // N*H
  float* transbuf = x2 + (size_t)NN * HH;            // N*H (also holds trans2 [R,N,C], same size)
  float* w1 = transbuf + (size_t)NN * HH;            // R*H*H
  float* w2 = w1 + RRL * HH * HH;                    // R*H*C
  int* perm = (int*)(w2 + RRL * HH * CC);            // E
  int* cnt = perm + EE;                              // R
  int* off = cnt + RRL;                              // R+1
  int* cur = off + RRL + 1;                          // R

  // edge bucketing by relation
  zero_cnt_kernel<<<1, 64, 0, stream>>>(cnt, cur);
  hist_kernel<<<EE / 256, 256, 0, stream>>>(r, cnt);
  scan_kernel<<<1, 1, 0, stream>>>(cnt, off, cur);
  scatter_kernel<<<EE / 256, 256, 0, stream>>>(r, cur, perm);

  // compose relation weight matrices for layers 1 & 2
  compose_w_kernel<<<(RRL * HH * HH + RRL * HH * CC) / 256, 256, 0, stream>>>(
      wcomp1, bases1, wcomp2, bases2, w1, w2);

  // ---- layer 0 ----
  l0_init_kernel<<<NN * HH / 4 / 256, 256, 0, stream>>>(h, loop0, bias0, x1);
  l0_edges_kernel<<<2048, 256, 0, stream>>>(src, dst, h, r, norm, wcomp0, bases0, x1);
  // relu folded into downstream GEMM A-loads

  // ---- layer 1 ----
  dim3 g1((NN + 63) / 64, 1);
  gemm_kernel<128, true, true><<<g1, 256, 0, stream>>>(x1, loop1, bias1, x2, NN);
  for (int rel = 0; rel < RRL; ++rel) {
    gemm_kernel<128, false, true>
        <<<g1, 256, 0, stream>>>(x1, w1 + (size_t)rel * HH * HH, nullptr, transbuf, NN);
    l1_gather_kernel<<<2048, 256, 0, stream>>>(src, dst, norm, perm, off, rel, transbuf, x2);
  }

  // ---- layer 2 ----
  gemm_kernel<16, true, true><<<g1, 256, 0, stream>>>(x2, loop2, bias2, out, NN);
  dim3 g2((NN + 63) / 64, RRL);
  gemm_kernel<16, false, true><<<g2, 256, 0, stream>>>(x2, w2, nullptr, transbuf, NN);
  l2_gather_kernel<<<2048, 256, 0, stream>>>(src, dst, r, norm, transbuf, out);
}

// Round 2
// 1412.302 us; speedup vs baseline: 1.6785x; 1.6785x over previous
//
#include <hip/hip_runtime.h>

#define NN 50000
#define HH 128
#define CC 16
#define RRL 8
#define BB 4
#define EE 800000
#define NT (RRL * NN)  // 400000 (rel,dst) buckets
#define SCAN_CHUNK 2048
#define NBLK_SCAN ((NT + SCAN_CHUNK - 1) / SCAN_CHUNK)  // 196

// ---------------- utility ----------------

__global__ __launch_bounds__(256) void zero_kernel(int* p, int n) {
  int i = blockIdx.x * 256 + threadIdx.x;
  if (i < n) p[i] = 0;
}

// ---------------- counting sort by key = rel*NN + dst ----------------

__global__ __launch_bounds__(256) void hist2_kernel(const int* __restrict__ r,
                                                    const int* __restrict__ dst,
                                                    int* __restrict__ cnt) {
  int e = blockIdx.x * 256 + threadIdx.x;
  if (e < EE) atomicAdd(&cnt[r[e] * NN + dst[e]], 1);
}

__global__ __launch_bounds__(256) void scanA_kernel(const int* __restrict__ cnt,
                                                    int* __restrict__ off,
                                                    int* __restrict__ partials) {
  __shared__ int sums[256];
  int tid = threadIdx.x;
  int base = blockIdx.x * SCAN_CHUNK + tid * 8;
  int v[8];
  int s = 0;
#pragma unroll
  for (int j = 0; j < 8; ++j) {
    int idx = base + j;
    v[j] = (idx < NT) ? cnt[idx] : 0;
    s += v[j];
  }
  sums[tid] = s;
  __syncthreads();
  for (int o = 1; o < 256; o <<= 1) {
    int t = (tid >= o) ? sums[tid - o] : 0;
    __syncthreads();
    sums[tid] += t;
    __syncthreads();
  }
  int run = sums[tid] - s;  // exclusive prefix within block
#pragma unroll
  for (int j = 0; j < 8; ++j) {
    int idx = base + j;
    if (idx < NT) off[idx] = run;
    run += v[j];
  }
  if (tid == 255) partials[blockIdx.x] = sums[255];
}

__global__ __launch_bounds__(256) void scanB_kernel(const int* __restrict__ partials,
                                                    int* __restrict__ pexcl) {
  __shared__ int sums[256];
  int tid = threadIdx.x;
  int p = (tid < NBLK_SCAN) ? partials[tid] : 0;
  sums[tid] = p;
  __syncthreads();
  for (int o = 1; o < 256; o <<= 1) {
    int t = (tid >= o) ? sums[tid - o] : 0;
    __syncthreads();
    sums[tid] += t;
    __syncthreads();
  }
  if (tid < NBLK_SCAN) pexcl[tid] = sums[tid] - p;
}

__global__ __launch_bounds__(256) void addC_kernel(int* __restrict__ off,
                                                   const int* __restrict__ pexcl,
                                                   int* __restrict__ cur) {
  int tid = threadIdx.x;
  int add = pexcl[blockIdx.x];
  int base = blockIdx.x * SCAN_CHUNK + tid * 8;
#pragma unroll
  for (int j = 0; j < 8; ++j) {
    int idx = base + j;
    if (idx < NT) {
      int v = off[idx] + add;
      off[idx] = v;
      cur[idx] = v;
    }
  }
  if (blockIdx.x == 0 && tid == 0) off[NT] = EE;
}

__global__ __launch_bounds__(256) void scatter2_kernel(
    const int* __restrict__ r, const int* __restrict__ dst, const int* __restrict__ src,
    const float* __restrict__ norm, int* __restrict__ cur, int* __restrict__ src_s,
    float* __restrict__ norm_s) {
  int e = blockIdx.x * 256 + threadIdx.x;
  if (e >= EE) return;
  int key = r[e] * NN + dst[e];
  int pos = atomicAdd(&cur[key], 1);
  src_s[pos] = src[e];
  norm_s[pos] = norm[e];
}

// ---------------- compose w1 = wcomp1@bases1, w2 = wcomp2@bases2 ----------------

__global__ __launch_bounds__(256) void compose_w_kernel(
    const float* __restrict__ wcomp1, const float* __restrict__ bases1,
    const float* __restrict__ wcomp2, const float* __restrict__ bases2,
    float* __restrict__ w1, float* __restrict__ w2) {
  int idx = blockIdx.x * 256 + threadIdx.x;
  if (idx < RRL * HH * HH) {
    int rr = idx / (HH * HH);
    int rem = idx - rr * HH * HH;
    float a = 0.f;
#pragma unroll
    for (int b = 0; b < BB; ++b) a += wcomp1[rr * BB + b] * bases1[b * HH * HH + rem];
    w1[idx] = a;
  } else {
    int j = idx - RRL * HH * HH;
    int rr = j / (HH * CC);
    int rem = j - rr * HH * CC;
    float a = 0.f;
#pragma unroll
    for (int b = 0; b < BB; ++b) a += wcomp2[rr * BB + b] * bases2[b * HH * CC + rem];
    w2[j] = a;
  }
}

// ---------------- layer 0: wave per dst, segment walk, no atomics ----------------

__global__ __launch_bounds__(256) void l0_seg_kernel(
    const int* __restrict__ h, const int* __restrict__ off2, const int* __restrict__ src_s,
    const float* __restrict__ norm_s, const float* __restrict__ wcomp0,
    const float* __restrict__ bases0, const float* __restrict__ loop0,
    const float* __restrict__ bias0, float* __restrict__ x1) {
  int lane = threadIdx.x & 63;
  int n = blockIdx.x * 4 + (threadIdx.x >> 6);
  if (n >= NN) return;
  float ax = 0.f, ay = 0.f;
  for (int z = 0; z < RRL; ++z) {
    float c0 = wcomp0[z * BB + 0];
    float c1 = wcomp0[z * BB + 1];
    float c2 = wcomp0[z * BB + 2];
    float c3 = wcomp0[z * BB + 3];
    int beg = off2[z * NN + n];
    int end = off2[z * NN + n + 1];
    for (int i = beg; i < end; ++i) {
      int s = src_s[i];
      int hs = h[s];
      float nrm = norm_s[i];
      float2 v0 = ((const float2*)(bases0 + ((size_t)(0 * NN) + hs) * HH))[lane];
      float2 v1 = ((const float2*)(bases0 + ((size_t)(1 * NN) + hs) * HH))[lane];
      float2 v2 = ((const float2*)(bases0 + ((size_t)(2 * NN) + hs) * HH))[lane];
      float2 v3 = ((const float2*)(bases0 + ((size_t)(3 * NN) + hs) * HH))[lane];
      float gx = c0 * v0.x + c1 * v1.x + c2 * v2.x + c3 * v3.x;
      float gy = c0 * v0.y + c1 * v1.y + c2 * v2.y + c3 * v3.y;
      ax = fmaf(nrm, gx, ax);
      ay = fmaf(nrm, gy, ay);
    }
  }
  int hn = h[n];
  float2 lv = ((const float2*)(loop0 + (size_t)hn * HH))[lane];
  float2 bv = ((const float2*)bias0)[lane];
  float2 o;
  o.x = ax + lv.x + bv.x;
  o.y = ay + lv.y + bv.y;
  ((float2*)(x1 + (size_t)n * HH))[lane] = o;
}

// ---------------- fp32 GEMM: out[z] = (relu?)A @ W[z] (+bias), A:[M,128], W:[128,F] ----------------

template <int F, bool BIAS, bool RELU_A>
__global__ __launch_bounds__(256) void gemm_kernel(const float* __restrict__ A,
                                                   const float* __restrict__ W,
                                                   const float* __restrict__ bias,
                                                   float* __restrict__ out, int M) {
  constexpr int K = HH;
  constexpr int KB = 64;
  constexpr int TM = 64;
  constexpr int WP = (F == 128) ? 132 : 20;
  const int z = blockIdx.y;
  const float* Wz = W + (size_t)z * K * F;
  float* outz = out + (size_t)z * M * F;
  const int row0 = blockIdx.x * TM;
  const int tid = threadIdx.x;

  __shared__ float xs[KB][TM + 4];
  __shared__ float ws[KB][WP];

  float acc[4][(F == 128) ? 8 : 1];
#pragma unroll
  for (int i = 0; i < 4; ++i)
#pragma unroll
    for (int j = 0; j < ((F == 128) ? 8 : 1); ++j) acc[i][j] = 0.f;
  float acc16[4] = {0.f, 0.f, 0.f, 0.f};

  for (int kb = 0; kb < K / KB; ++kb) {
    if (kb) __syncthreads();
#pragma unroll
    for (int i = 0; i < TM * KB / 256; ++i) {
      int flat = tid + i * 256;
      int rrow = flat >> 6;
      int kk = flat & 63;
      int g = row0 + rrow;
      float v = (g < M) ? A[(size_t)g * K + kb * KB + kk] : 0.f;
      if (RELU_A) v = fmaxf(v, 0.f);
      xs[kk][rrow] = v;
    }
#pragma unroll
    for (int i = 0; i < KB * F / 256; ++i) {
      int flat = tid + i * 256;
      int kk = flat / F;
      int ff = flat - kk * F;
      ws[kk][ff] = Wz[(size_t)(kb * KB + kk) * F + ff];
    }
    __syncthreads();

    if constexpr (F == 128) {
      const int r0 = (tid & 15) * 4;
      const int c0 = (tid >> 4) * 8;
#pragma unroll 4
      for (int k = 0; k < KB; ++k) {
        float4 xv = *(const float4*)&xs[k][r0];
        float4 wa = *(const float4*)&ws[k][c0];
        float4 wb = *(const float4*)&ws[k][c0 + 4];
        float xr[4] = {xv.x, xv.y, xv.z, xv.w};
        float wc[8] = {wa.x, wa.y, wa.z, wa.w, wb.x, wb.y, wb.z, wb.w};
#pragma unroll
        for (int i = 0; i < 4; ++i)
#pragma unroll
          for (int j = 0; j < 8; ++j) acc[i][j] = fmaf(xr[i], wc[j], acc[i][j]);
      }
    } else {
      const int rrow = tid >> 2;
      const int c0 = (tid & 3) * 4;
#pragma unroll 4
      for (int k = 0; k < KB; ++k) {
        float xv = xs[k][rrow];
        float4 wv = *(const float4*)&ws[k][c0];
        acc16[0] = fmaf(xv, wv.x, acc16[0]);
        acc16[1] = fmaf(xv, wv.y, acc16[1]);
        acc16[2] = fmaf(xv, wv.z, acc16[2]);
        acc16[3] = fmaf(xv, wv.w, acc16[3]);
      }
    }
  }

  if constexpr (F == 128) {
    const int r0 = (tid & 15) * 4;
    const int c0 = (tid >> 4) * 8;
    float4 b0 = make_float4(0.f, 0.f, 0.f, 0.f), b1 = b0;
    if (BIAS) {
      b0 = *(const float4*)&bias[c0];
      b1 = *(const float4*)&bias[c0 + 4];
    }
#pragma unroll
    for (int i = 0; i < 4; ++i) {
      int g = row0 + r0 + i;
      if (g >= M) continue;
      float4 o0, o1;
      o0.x = acc[i][0] + b0.x; o0.y = acc[i][1] + b0.y;
      o0.z = acc[i][2] + b0.z; o0.w = acc[i][3] + b0.w;
      o1.x = acc[i][4] + b1.x; o1.y = acc[i][5] + b1.y;
      o1.z = acc[i][6] + b1.z; o1.w = acc[i][7] + b1.w;
      *(float4*)&outz[(size_t)g * F + c0] = o0;
      *(float4*)&outz[(size_t)g * F + c0 + 4] = o1;
    }
  } else {
    const int rrow = tid >> 2;
    const int c0 = (tid & 3) * 4;
    int g = row0 + rrow;
    if (g < M) {
      float4 bv = make_float4(0.f, 0.f, 0.f, 0.f);
      if (BIAS) bv = *(const float4*)&bias[c0];
      float4 o;
      o.x = acc16[0] + bv.x; o.y = acc16[1] + bv.y;
      o.z = acc16[2] + bv.z; o.w = acc16[3] + bv.w;
      *(float4*)&outz[(size_t)g * F + c0] = o;
    }
  }
}

// ---------------- layer 1 gather: wave per dst, one relation, non-atomic RMW ----------------

__global__ __launch_bounds__(256) void l1_seg_kernel(
    const int* __restrict__ off2, const int* __restrict__ src_s,
    const float* __restrict__ norm_s, int z, const float* __restrict__ trans,
    float* __restrict__ x2) {
  int lane = threadIdx.x & 63;
  int n = blockIdx.x * 4 + (threadIdx.x >> 6);
  if (n >= NN) return;
  int beg = off2[z * NN + n];
  int end = off2[z * NN + n + 1];
  if (beg == end) return;
  float ax = 0.f, ay = 0.f;
  for (int i = beg; i < end; ++i) {
    int s = src_s[i];
    float nrm = norm_s[i];
    float2 v = ((const float2*)(trans + (size_t)s * HH))[lane];
    ax = fmaf(nrm, v.x, ax);
    ay = fmaf(nrm, v.y, ay);
  }
  float2* o = (float2*)(x2 + (size_t)n * HH) + lane;
  float2 cv = *o;
  cv.x += ax;
  cv.y += ay;
  *o = cv;
}

// ---------------- layer 2 gather: 16 lanes per dst, all relations, non-atomic RMW ----------------

__global__ __launch_bounds__(256) void l2_seg_kernel(
    const int* __restrict__ off2, const int* __restrict__ src_s,
    const float* __restrict__ norm_s, const float* __restrict__ trans2,
    float* __restrict__ outp) {
  int l16 = threadIdx.x & 15;
  int n = (blockIdx.x * 256 + threadIdx.x) >> 4;
  if (n >= NN) return;
  float a = 0.f;
  for (int z = 0; z < RRL; ++z) {
    int beg = off2[z * NN + n];
    int end = off2[z * NN + n + 1];
    for (int i = beg; i < end; ++i) {
      int s = src_s[i];
      float nrm = norm_s[i];
      a = fmaf(nrm, trans2[((size_t)z * NN + s) * CC + l16], a);
    }
  }
  outp[(size_t)n * CC + l16] += a;
}

// ---------------- launch ----------------

extern "C" void kernel_launch(void* const* d_in, const int* in_sizes, int n_in,
                              void* d_out, int out_size, void* d_ws, size_t ws_size,
                              hipStream_t stream) {
  const int* src = (const int*)d_in[0];
  const int* dst = (const int*)d_in[1];
  const int* h = (const int*)d_in[2];
  const int* r = (const int*)d_in[3];
  const float* norm = (const float*)d_in[4];
  const float* bases0 = (const float*)d_in[5];
  const float* wcomp0 = (const float*)d_in[6];
  const float* loop0 = (const float*)d_in[7];
  const float* bias0 = (const float*)d_in[8];
  const float* bases1 = (const float*)d_in[9];
  const float* wcomp1 = (const float*)d_in[10];
  const float* loop1 = (const float*)d_in[11];
  const float* bias1 = (const float*)d_in[12];
  const float* bases2 = (const float*)d_in[13];
  const float* wcomp2 = (const float*)d_in[14];
  const float* loop2 = (const float*)d_in[15];
  const float* bias2 = (const float*)d_in[16];
  float* out = (float*)d_out;

  float* ws = (float*)d_ws;
  float* x1 = ws;                                    // N*H
  float* x2 = x1 + (size_t)NN * HH;                  // N*H
  float* transbuf = x2 + (size_t)NN * HH;            // N*H (layer1 per-rel trans; layer2 trans2 [R,N,C])
  float* w1 = transbuf + (size_t)NN * HH;            // R*H*H
  float* w2 = w1 + RRL * HH * HH;                    // R*H*C
  float* norm_s = w2 + RRL * HH * CC;                // E
  int* src_s = (int*)(norm_s + EE);                  // E
  int* off2 = src_s + EE;                            // NT+1
  int* cur2 = off2 + NT + 1;                         // NT
  int* cnt2 = cur2 + NT;                             // NT
  int* partials = cnt2 + NT;                         // NBLK_SCAN
  int* pexcl = partials + 256;                       // NBLK_SCAN

  // ---- counting sort of edges by (rel, dst) ----
  zero_kernel<<<(NT + 255) / 256, 256, 0, stream>>>(cnt2, NT);
  hist2_kernel<<<(EE + 255) / 256, 256, 0, stream>>>(r, dst, cnt2);
  scanA_kernel<<<NBLK_SCAN, 256, 0, stream>>>(cnt2, off2, partials);
  scanB_kernel<<<1, 256, 0, stream>>>(partials, pexcl);
  addC_kernel<<<NBLK_SCAN, 256, 0, stream>>>(off2, pexcl, cur2);
  scatter2_kernel<<<(EE + 255) / 256, 256, 0, stream>>>(r, dst, src, norm, cur2, src_s, norm_s);

  // ---- compose relation weight matrices for layers 1 & 2 ----
  compose_w_kernel<<<(RRL * HH * HH + RRL * HH * CC) / 256, 256, 0, stream>>>(
      wcomp1, bases1, wcomp2, bases2, w1, w2);

  // ---- layer 0: segment aggregation (fuses loop0 + bias0) ----
  l0_seg_kernel<<<(NN + 3) / 4, 256, 0, stream>>>(h, off2, src_s, norm_s, wcomp0, bases0,
                                                  loop0, bias0, x1);

  // ---- layer 1 ----
  dim3 g1((NN + 63) / 64, 1);
  gemm_kernel<128, true, true><<<g1, 256, 0, stream>>>(x1, loop1, bias1, x2, NN);
  for (int rel = 0; rel < RRL; ++rel) {
    gemm_kernel<128, false, true>
        <<<g1, 256, 0, stream>>>(x1, w1 + (size_t)rel * HH * HH, nullptr, transbuf, NN);
    l1_seg_kernel<<<(NN + 3) / 4, 256, 0, stream>>>(off2, src_s, norm_s, rel, transbuf, x2);
  }

  // ---- layer 2 ----
  gemm_kernel<16, true, true><<<g1, 256, 0, stream>>>(x2, loop2, bias2, out, NN);
  dim3 g2((NN + 63) / 64, RRL);
  gemm_kernel<16, false, true><<<g2, 256, 0, stream>>>(x2, w2, nullptr, transbuf, NN);
  l2_seg_kernel<<<(NN * 16 + 255) / 256, 256, 0, stream>>>(off2, src_s, norm_s, transbuf, out);
}

// Round 3
// 669.689 us; speedup vs baseline: 3.5398x; 2.1089x over previous
//
#include <hip/hip_runtime.h>

#define NN 50000
#define NP 50048            // padded rows (multiple of 128)
#define HH 128
#define CC 16
#define RRL 8
#define BB 4
#define EE 800000
#define NT (RRL * NN)       // 400000 (rel,dst) buckets
#define SCAN_CHUNK 2048
#define NBLK_SCAN ((NT + SCAN_CHUNK - 1) / SCAN_CHUNK)  // 196

typedef short bf16x8_t __attribute__((ext_vector_type(8)));
typedef float f32x4_t __attribute__((ext_vector_type(4)));

__device__ __forceinline__ unsigned short f2bf(float f) {
  unsigned int x = __float_as_uint(f);
  unsigned int r = x + 0x7fffu + ((x >> 16) & 1u);
  return (unsigned short)(r >> 16);
}

// ---------------- utility ----------------

__global__ __launch_bounds__(256) void zero_kernel(int* p, int n) {
  int i = blockIdx.x * 256 + threadIdx.x;
  if (i < n) p[i] = 0;
}

// ---------------- counting sort by key = rel*NN + dst ----------------

__global__ __launch_bounds__(256) void hist2_kernel(const int* __restrict__ r,
                                                    const int* __restrict__ dst,
                                                    int* __restrict__ cnt) {
  int e = blockIdx.x * 256 + threadIdx.x;
  if (e < EE) atomicAdd(&cnt[r[e] * NN + dst[e]], 1);
}

__global__ __launch_bounds__(256) void scanA_kernel(const int* __restrict__ cnt,
                                                    int* __restrict__ off,
                                                    int* __restrict__ partials) {
  __shared__ int sums[256];
  int tid = threadIdx.x;
  int base = blockIdx.x * SCAN_CHUNK + tid * 8;
  int v[8];
  int s = 0;
#pragma unroll
  for (int j = 0; j < 8; ++j) {
    int idx = base + j;
    v[j] = (idx < NT) ? cnt[idx] : 0;
    s += v[j];
  }
  sums[tid] = s;
  __syncthreads();
  for (int o = 1; o < 256; o <<= 1) {
    int t = (tid >= o) ? sums[tid - o] : 0;
    __syncthreads();
    sums[tid] += t;
    __syncthreads();
  }
  int run = sums[tid] - s;
#pragma unroll
  for (int j = 0; j < 8; ++j) {
    int idx = base + j;
    if (idx < NT) off[idx] = run;
    run += v[j];
  }
  if (tid == 255) partials[blockIdx.x] = sums[255];
}

__global__ __launch_bounds__(256) void scanB_kernel(const int* __restrict__ partials,
                                                    int* __restrict__ pexcl) {
  __shared__ int sums[256];
  int tid = threadIdx.x;
  int p = (tid < NBLK_SCAN) ? partials[tid] : 0;
  sums[tid] = p;
  __syncthreads();
  for (int o = 1; o < 256; o <<= 1) {
    int t = (tid >= o) ? sums[tid - o] : 0;
    __syncthreads();
    sums[tid] += t;
    __syncthreads();
  }
  if (tid < NBLK_SCAN) pexcl[tid] = sums[tid] - p;
}

__global__ __launch_bounds__(256) void addC_kernel(int* __restrict__ off,
                                                   const int* __restrict__ pexcl,
                                                   int* __restrict__ cur) {
  int tid = threadIdx.x;
  int add = pexcl[blockIdx.x];
  int base = blockIdx.x * SCAN_CHUNK + tid * 8;
#pragma unroll
  for (int j = 0; j < 8; ++j) {
    int idx = base + j;
    if (idx < NT) {
      int v = off[idx] + add;
      off[idx] = v;
      cur[idx] = v;
    }
  }
  if (blockIdx.x == 0 && tid == 0) off[NT] = EE;
}

__global__ __launch_bounds__(256) void scatter2_kernel(
    const int* __restrict__ r, const int* __restrict__ dst, const int* __restrict__ src,
    const float* __restrict__ norm, int* __restrict__ cur, int* __restrict__ src_s,
    float* __restrict__ norm_s) {
  int e = blockIdx.x * 256 + threadIdx.x;
  if (e >= EE) return;
  int key = r[e] * NN + dst[e];
  int pos = atomicAdd(&cur[key], 1);
  src_s[pos] = src[e];
  norm_s[pos] = norm[e];
}

// ---------------- compose small weights (bf16, transposed [n][k]) ----------------

__global__ __launch_bounds__(256) void compose_small_kernel(
    const float* __restrict__ wcomp1, const float* __restrict__ bases1,
    const float* __restrict__ loop1, const float* __restrict__ wcomp2,
    const float* __restrict__ bases2, const float* __restrict__ loop2,
    unsigned short* __restrict__ w1t, unsigned short* __restrict__ loop1t,
    unsigned short* __restrict__ w2t, unsigned short* __restrict__ loop2t) {
  int idx = blockIdx.x * 256 + threadIdx.x;
  if (idx < RRL * HH * HH) {  // w1t[z][n][k]
    int z = idx >> 14;
    int rem = idx & 16383;
    int n = rem >> 7, k = rem & 127;
    float a = 0.f;
#pragma unroll
    for (int b = 0; b < BB; ++b)
      a += wcomp1[z * BB + b] * bases1[((size_t)b * HH + k) * HH + n];
    w1t[idx] = f2bf(a);
    return;
  }
  int j = idx - RRL * HH * HH;
  if (j < HH * HH) {  // loop1t[n][k]
    int n = j >> 7, k = j & 127;
    loop1t[j] = f2bf(loop1[k * HH + n]);
    return;
  }
  j -= HH * HH;
  if (j < RRL * CC * HH) {  // w2t[z][n][k]
    int z = j >> 11;
    int rem = j & 2047;
    int n = rem >> 7, k = rem & 127;
    float a = 0.f;
#pragma unroll
    for (int b = 0; b < BB; ++b)
      a += wcomp2[z * BB + b] * bases2[((size_t)b * HH + k) * CC + n];
    w2t[j] = f2bf(a);
    return;
  }
  j -= RRL * CC * HH;
  if (j < CC * HH) {  // loop2t[n][k]
    int n = j >> 7, k = j & 127;
    loop2t[j] = f2bf(loop2[k * CC + n]);
  }
}

// ---------------- w0 bf16 table: w0b[z][m][f] = sum_b wcomp0[z,b]*bases0[b,m,f] ----------------

__global__ __launch_bounds__(256) void w0b_build_kernel(const float* __restrict__ bases0,
                                                        const float* __restrict__ wcomp0,
                                                        unsigned short* __restrict__ w0b) {
  int idx = blockIdx.x * 256 + threadIdx.x;  // m*32 + c (c = float4 chunk)
  int m = idx >> 5, c = idx & 31;
  if (m >= NN) return;
  float4 b0 = ((const float4*)(bases0 + ((size_t)0 * NN + m) * HH))[c];
  float4 b1 = ((const float4*)(bases0 + ((size_t)1 * NN + m) * HH))[c];
  float4 b2 = ((const float4*)(bases0 + ((size_t)2 * NN + m) * HH))[c];
  float4 b3 = ((const float4*)(bases0 + ((size_t)3 * NN + m) * HH))[c];
#pragma unroll
  for (int z = 0; z < RRL; ++z) {
    float c0 = wcomp0[z * BB + 0], c1 = wcomp0[z * BB + 1];
    float c2 = wcomp0[z * BB + 2], c3 = wcomp0[z * BB + 3];
    float vx = c0 * b0.x + c1 * b1.x + c2 * b2.x + c3 * b3.x;
    float vy = c0 * b0.y + c1 * b1.y + c2 * b2.y + c3 * b3.y;
    float vz = c0 * b0.z + c1 * b1.z + c2 * b2.z + c3 * b3.z;
    float vw = c0 * b0.w + c1 * b1.w + c2 * b2.w + c3 * b3.w;
    uint2 pk;
    pk.x = ((unsigned)f2bf(vy) << 16) | f2bf(vx);
    pk.y = ((unsigned)f2bf(vw) << 16) | f2bf(vz);
    ((uint2*)(w0b + ((size_t)z * NP + m) * HH))[c] = pk;
  }
}

// ---------------- layer 0: wave per dst, bf16 w0 gather (big path) ----------------

__global__ __launch_bounds__(256) void l0_seg_big_kernel(
    const int* __restrict__ h, const int* __restrict__ off2, const int* __restrict__ src_s,
    const float* __restrict__ norm_s, const unsigned short* __restrict__ w0b,
    const float* __restrict__ loop0, const float* __restrict__ bias0,
    unsigned short* __restrict__ x1b) {
  int lane = threadIdx.x & 63;
  int n = blockIdx.x * 4 + (threadIdx.x >> 6);
  if (n >= NP) return;
  unsigned int* orow = (unsigned int*)x1b + (size_t)n * 64 + lane;
  if (n >= NN) { *orow = 0u; return; }
  float ax = 0.f, ay = 0.f;
  for (int z = 0; z < RRL; ++z) {
    int beg = off2[z * NN + n];
    int end = off2[z * NN + n + 1];
    for (int i = beg; i < end; ++i) {
      int s = src_s[i];
      int hs = h[s];
      float nrm = norm_s[i];
      unsigned int u = *(const unsigned int*)(w0b + ((size_t)z * NP + hs) * HH + lane * 2);
      ax = fmaf(nrm, __uint_as_float(u << 16), ax);
      ay = fmaf(nrm, __uint_as_float(u & 0xffff0000u), ay);
    }
  }
  int hn = h[n];
  float2 lv = ((const float2*)(loop0 + (size_t)hn * HH))[lane];
  float2 bv = ((const float2*)bias0)[lane];
  float ox = fmaxf(ax + lv.x + bv.x, 0.f);
  float oy = fmaxf(ay + lv.y + bv.y, 0.f);
  *orow = ((unsigned)f2bf(oy) << 16) | f2bf(ox);
}

// ---------------- layer 0 fallback: fp32 bases0 gather (small path) ----------------

__global__ __launch_bounds__(256) void l0_seg_small_kernel(
    const int* __restrict__ h, const int* __restrict__ off2, const int* __restrict__ src_s,
    const float* __restrict__ norm_s, const float* __restrict__ wcomp0,
    const float* __restrict__ bases0, const float* __restrict__ loop0,
    const float* __restrict__ bias0, unsigned short* __restrict__ x1b) {
  int lane = threadIdx.x & 63;
  int n = blockIdx.x * 4 + (threadIdx.x >> 6);
  if (n >= NP) return;
  unsigned int* orow = (unsigned int*)x1b + (size_t)n * 64 + lane;
  if (n >= NN) { *orow = 0u; return; }
  float ax = 0.f, ay = 0.f;
  for (int z = 0; z < RRL; ++z) {
    float c0 = wcomp0[z * BB + 0], c1 = wcomp0[z * BB + 1];
    float c2 = wcomp0[z * BB + 2], c3 = wcomp0[z * BB + 3];
    int beg = off2[z * NN + n];
    int end = off2[z * NN + n + 1];
    for (int i = beg; i < end; ++i) {
      int s = src_s[i];
      int hs = h[s];
      float nrm = norm_s[i];
      float2 v0 = ((const float2*)(bases0 + ((size_t)0 * NN + hs) * HH))[lane];
      float2 v1 = ((const float2*)(bases0 + ((size_t)1 * NN + hs) * HH))[lane];
      float2 v2 = ((const float2*)(bases0 + ((size_t)2 * NN + hs) * HH))[lane];
      float2 v3 = ((const float2*)(bases0 + ((size_t)3 * NN + hs) * HH))[lane];
      float gx = c0 * v0.x + c1 * v1.x + c2 * v2.x + c3 * v3.x;
      float gy = c0 * v0.y + c1 * v1.y + c2 * v2.y + c3 * v3.y;
      ax = fmaf(nrm, gx, ax);
      ay = fmaf(nrm, gy, ay);
    }
  }
  int hn = h[n];
  float2 lv = ((const float2*)(loop0 + (size_t)hn * HH))[lane];
  float2 bv = ((const float2*)bias0)[lane];
  float ox = fmaxf(ax + lv.x + bv.x, 0.f);
  float oy = fmaxf(ay + lv.y + bv.y, 0.f);
  *orow = ((unsigned)f2bf(oy) << 16) | f2bf(ox);
}

// ---------------- bf16 MFMA GEMM: C = A(bf16 [NP x128]) @ Bt(bf16 [F x 128])^T ----------------
// Bt is row-major [n][k] (pre-transposed). out: bf16 (trans) or fp32+bias (selfloop).

template <int F>
__global__ __launch_bounds__(256) void gemm_mfma_kernel(
    const unsigned short* __restrict__ A, const unsigned short* __restrict__ Ball,
    unsigned short* __restrict__ outb, float* __restrict__ outf,
    const float* __restrict__ bias, int Mvalid) {
  constexpr int ROWS = (F == 128) ? 64 : 128;
  constexpr int CT = (F == 128) ? 4 : 1;
  constexpr int LP = 136;  // padded row stride (ushorts): 272B -> bank offset 4/row, 2-way max
  __shared__ unsigned short Alds[ROWS * LP];
  __shared__ unsigned short Blds[F * LP];
  const int z = blockIdx.y;
  const int row0 = blockIdx.x * ROWS;
  const int tid = threadIdx.x;
  const unsigned short* B = Ball + (size_t)z * 128 * F;

#pragma unroll
  for (int it = 0; it < ROWS * 16 / 256; ++it) {
    int flat = tid + it * 256;
    int row = flat >> 4, c8 = flat & 15;
    uint4 v = *(const uint4*)(A + ((size_t)(row0 + row)) * 128 + c8 * 8);
    *(uint4*)(&Alds[row * LP + c8 * 8]) = v;
  }
#pragma unroll
  for (int it = 0; it < F * 16 / 256; ++it) {
    int flat = tid + it * 256;
    int row = flat >> 4, c8 = flat & 15;
    uint4 v = *(const uint4*)(B + (size_t)row * 128 + c8 * 8);
    *(uint4*)(&Blds[row * LP + c8 * 8]) = v;
  }
  __syncthreads();

  const int w = tid >> 6, lane = tid & 63;
  const int quad = lane >> 4, l15 = lane & 15;
  const int rb = (F == 128) ? (w >> 1) * 32 : w * 32;
  const int cb = (F == 128) ? (w & 1) * 64 : 0;

  f32x4_t acc[2][CT];
#pragma unroll
  for (int rt = 0; rt < 2; ++rt)
#pragma unroll
    for (int ct = 0; ct < CT; ++ct) acc[rt][ct] = (f32x4_t){0.f, 0.f, 0.f, 0.f};

#pragma unroll
  for (int ks = 0; ks < 4; ++ks) {
    int ko = ks * 32 + quad * 8;
    bf16x8_t af[2], bfr[CT];
#pragma unroll
    for (int rt = 0; rt < 2; ++rt)
      af[rt] = *(const bf16x8_t*)(&Alds[(rb + rt * 16 + l15) * LP + ko]);
#pragma unroll
    for (int ct = 0; ct < CT; ++ct)
      bfr[ct] = *(const bf16x8_t*)(&Blds[(cb + ct * 16 + l15) * LP + ko]);
#pragma unroll
    for (int rt = 0; rt < 2; ++rt)
#pragma unroll
      for (int ct = 0; ct < CT; ++ct)
        acc[rt][ct] =
            __builtin_amdgcn_mfma_f32_16x16x32_bf16(af[rt], bfr[ct], acc[rt][ct], 0, 0, 0);
  }

  if (outf) {
#pragma unroll
    for (int rt = 0; rt < 2; ++rt)
#pragma unroll
      for (int ct = 0; ct < CT; ++ct) {
        int n = cb + ct * 16 + l15;
        float bv = bias[n];
#pragma unroll
        for (int i = 0; i < 4; ++i) {
          int m = row0 + rb + rt * 16 + quad * 4 + i;
          if (m < Mvalid) outf[(size_t)m * F + n] = acc[rt][ct][i] + bv;
        }
      }
  } else {
    unsigned short* ob = outb + (size_t)z * NP * F;
#pragma unroll
    for (int rt = 0; rt < 2; ++rt)
#pragma unroll
      for (int ct = 0; ct < CT; ++ct) {
        int n = cb + ct * 16 + l15;
#pragma unroll
        for (int i = 0; i < 4; ++i) {
          int m = row0 + rb + rt * 16 + quad * 4 + i;
          ob[(size_t)m * F + n] = f2bf(acc[rt][ct][i]);
        }
      }
  }
}

// ---------------- layer 1 gather (big): all rels merged, bf16 trans, fused relu+bf16 ----------------

__global__ __launch_bounds__(256) void l1_seg_merged_kernel(
    const int* __restrict__ off2, const int* __restrict__ src_s,
    const float* __restrict__ norm_s, const unsigned short* __restrict__ transb,
    const float* __restrict__ x2init, unsigned short* __restrict__ x2b) {
  int lane = threadIdx.x & 63;
  int n = blockIdx.x * 4 + (threadIdx.x >> 6);
  if (n >= NP) return;
  float ax = 0.f, ay = 0.f;
  if (n < NN) {
    for (int z = 0; z < RRL; ++z) {
      int beg = off2[z * NN + n];
      int end = off2[z * NN + n + 1];
      for (int i = beg; i < end; ++i) {
        int s = src_s[i];
        float nrm = norm_s[i];
        unsigned int u = *(const unsigned int*)(transb + ((size_t)z * NP + s) * HH + lane * 2);
        ax = fmaf(nrm, __uint_as_float(u << 16), ax);
        ay = fmaf(nrm, __uint_as_float(u & 0xffff0000u), ay);
      }
    }
  }
  float2 bse = ((const float2*)(x2init + (size_t)n * HH))[lane];
  float ox = fmaxf(ax + bse.x, 0.f);
  float oy = fmaxf(ay + bse.y, 0.f);
  ((unsigned int*)x2b)[(size_t)n * 64 + lane] = ((unsigned)f2bf(oy) << 16) | f2bf(ox);
}

// ---------------- layer 1 gather (small): one rel, RMW into fp32 x2init ----------------

__global__ __launch_bounds__(256) void l1_seg_perrel_kernel(
    const int* __restrict__ off2, const int* __restrict__ src_s,
    const float* __restrict__ norm_s, int z, const unsigned short* __restrict__ transbuf,
    float* __restrict__ x2init) {
  int lane = threadIdx.x & 63;
  int n = blockIdx.x * 4 + (threadIdx.x >> 6);
  if (n >= NN) return;
  int beg = off2[z * NN + n];
  int end = off2[z * NN + n + 1];
  if (beg == end) return;
  float ax = 0.f, ay = 0.f;
  for (int i = beg; i < end; ++i) {
    int s = src_s[i];
    float nrm = norm_s[i];
    unsigned int u = *(const unsigned int*)(transbuf + (size_t)s * HH + lane * 2);
    ax = fmaf(nrm, __uint_as_float(u << 16), ax);
    ay = fmaf(nrm, __uint_as_float(u & 0xffff0000u), ay);
  }
  float2* o = (float2*)(x2init + (size_t)n * HH) + lane;
  float2 cv = *o;
  cv.x += ax;
  cv.y += ay;
  *o = cv;
}

__global__ __launch_bounds__(256) void x2fin_kernel(const float* __restrict__ x2init,
                                                    unsigned short* __restrict__ x2b) {
  int idx = blockIdx.x * 256 + threadIdx.x;  // uint (2-elem) index, NP*64 total
  float2 v = ((const float2*)x2init)[idx];
  ((unsigned int*)x2b)[idx] =
      ((unsigned)f2bf(fmaxf(v.y, 0.f)) << 16) | f2bf(fmaxf(v.x, 0.f));
}

// ---------------- layer 2 gather: 16 lanes/dst, all rels, non-atomic RMW on out ----------------

__global__ __launch_bounds__(256) void l2_seg_kernel(
    const int* __restrict__ off2, const int* __restrict__ src_s,
    const float* __restrict__ norm_s, const unsigned short* __restrict__ trans2,
    float* __restrict__ outp) {
  int l16 = threadIdx.x & 15;
  int n = (blockIdx.x * 256 + threadIdx.x) >> 4;
  if (n >= NN) return;
  float a = 0.f;
  for (int z = 0; z < RRL; ++z) {
    int beg = off2[z * NN + n];
    int end = off2[z * NN + n + 1];
    for (int i = beg; i < end; ++i) {
      int s = src_s[i];
      float nrm = norm_s[i];
      unsigned int us = trans2[((size_t)z * NP + s) * CC + l16];
      a = fmaf(nrm, __uint_as_float(us << 16), a);
    }
  }
  outp[(size_t)n * CC + l16] += a;
}

// ---------------- launch ----------------

extern "C" void kernel_launch(void* const* d_in, const int* in_sizes, int n_in,
                              void* d_out, int out_size, void* d_ws, size_t ws_size,
                              hipStream_t stream) {
  const int* src = (const int*)d_in[0];
  const int* dst = (const int*)d_in[1];
  const int* h = (const int*)d_in[2];
  const int* r = (const int*)d_in[3];
  const float* norm = (const float*)d_in[4];
  const float* bases0 = (const float*)d_in[5];
  const float* wcomp0 = (const float*)d_in[6];
  const float* loop0 = (const float*)d_in[7];
  const float* bias0 = (const float*)d_in[8];
  const float* bases1 = (const float*)d_in[9];
  const float* wcomp1 = (const float*)d_in[10];
  const float* loop1 = (const float*)d_in[11];
  const float* bias1 = (const float*)d_in[12];
  const float* bases2 = (const float*)d_in[13];
  const float* wcomp2 = (const float*)d_in[14];
  const float* loop2 = (const float*)d_in[15];
  const float* bias2 = (const float*)d_in[16];
  float* out = (float*)d_out;

  char* p = (char*)d_ws;
  auto alloc = [&](size_t bytes) {
    char* q = p;
    p += (bytes + 255) & ~(size_t)255;
    return q;
  };
  unsigned short* x1b = (unsigned short*)alloc((size_t)NP * HH * 2);
  unsigned short* x2b = (unsigned short*)alloc((size_t)NP * HH * 2);
  float* x2init = (float*)alloc((size_t)NP * HH * 4);
  unsigned short* trans2 = (unsigned short*)alloc((size_t)RRL * NP * CC * 2);
  unsigned short* w1t = (unsigned short*)alloc((size_t)RRL * HH * HH * 2);
  unsigned short* loop1t = (unsigned short*)alloc((size_t)HH * HH * 2);
  unsigned short* w2t = (unsigned short*)alloc((size_t)RRL * CC * HH * 2);
  unsigned short* loop2t = (unsigned short*)alloc((size_t)CC * HH * 2);
  float* norm_s = (float*)alloc((size_t)EE * 4);
  int* src_s = (int*)alloc((size_t)EE * 4);
  int* off2 = (int*)alloc((size_t)(NT + 1) * 4);
  int* cur2 = (int*)alloc((size_t)NT * 4);
  int* cnt2 = (int*)alloc((size_t)NT * 4);
  int* partials = (int*)alloc(1024);
  int* pexcl = (int*)alloc(1024);
  unsigned short* BIG = (unsigned short*)p;  // w0b / trans_b (big) or per-rel transbuf (small)
  size_t used = (size_t)(p - (char*)d_ws);
  size_t big_bytes = (size_t)RRL * NP * HH * 2;   // 102.5 MB
  size_t small_bytes = (size_t)NP * HH * 2;       // 12.8 MB
  bool big = (used + big_bytes) <= ws_size;
  (void)small_bytes;

  // ---- counting sort of edges by (rel, dst) ----
  zero_kernel<<<(NT + 255) / 256, 256, 0, stream>>>(cnt2, NT);
  hist2_kernel<<<(EE + 255) / 256, 256, 0, stream>>>(r, dst, cnt2);
  scanA_kernel<<<NBLK_SCAN, 256, 0, stream>>>(cnt2, off2, partials);
  scanB_kernel<<<1, 256, 0, stream>>>(partials, pexcl);
  addC_kernel<<<NBLK_SCAN, 256, 0, stream>>>(off2, pexcl, cur2);
  scatter2_kernel<<<(EE + 255) / 256, 256, 0, stream>>>(r, dst, src, norm, cur2, src_s, norm_s);

  // ---- compose bf16 weights (transposed [n][k]) ----
  compose_small_kernel<<<648, 256, 0, stream>>>(wcomp1, bases1, loop1, wcomp2, bases2, loop2,
                                                w1t, loop1t, w2t, loop2t);

  // ---- layer 0 ----
  if (big) {
    w0b_build_kernel<<<(NN * 32) / 256, 256, 0, stream>>>(bases0, wcomp0, BIG);
    l0_seg_big_kernel<<<NP / 4, 256, 0, stream>>>(h, off2, src_s, norm_s, BIG, loop0, bias0,
                                                  x1b);
  } else {
    l0_seg_small_kernel<<<NP / 4, 256, 0, stream>>>(h, off2, src_s, norm_s, wcomp0, bases0,
                                                    loop0, bias0, x1b);
  }

  // ---- layer 1 ----
  // self-loop first: x2init = x1b @ loop1t^T + bias1 (fp32, all NP rows)
  gemm_mfma_kernel<128><<<dim3(NP / 64, 1), 256, 0, stream>>>(x1b, loop1t, nullptr, x2init,
                                                              bias1, NP);
  if (big) {
    // all 8 relation transforms in one launch -> BIG (overwrites dead w0b)
    gemm_mfma_kernel<128><<<dim3(NP / 64, RRL), 256, 0, stream>>>(x1b, w1t, BIG, nullptr,
                                                                  nullptr, NP);
    l1_seg_merged_kernel<<<NP / 4, 256, 0, stream>>>(off2, src_s, norm_s, BIG, x2init, x2b);
  } else {
    for (int z = 0; z < RRL; ++z) {
      gemm_mfma_kernel<128><<<dim3(NP / 64, 1), 256, 0, stream>>>(
          x1b, w1t + (size_t)z * HH * HH, BIG, nullptr, nullptr, NP);
      l1_seg_perrel_kernel<<<NP / 4, 256, 0, stream>>>(off2, src_s, norm_s, z, BIG, x2init);
    }
    x2fin_kernel<<<NP * 64 / 256, 256, 0, stream>>>(x2init, x2b);
  }

  // ---- layer 2 ----
  gemm_mfma_kernel<16><<<dim3(NP / 128, RRL), 256, 0, stream>>>(x2b, w2t, trans2, nullptr,
                                                                nullptr, NP);
  gemm_mfma_kernel<16><<<dim3(NP / 128, 1), 256, 0, stream>>>(x2b, loop2t, nullptr, out,
                                                              bias2, NN);
  l2_seg_kernel<<<(NN * 16 + 255) / 256, 256, 0, stream>>>(off2, src_s, norm_s, trans2, out);
}

// Round 4
// 602.836 us; speedup vs baseline: 3.9324x; 1.1109x over previous
//
#include <hip/hip_runtime.h>

#define NN 50000
#define NP 50048            // padded rows (multiple of 128)
#define HH 128
#define CC 16
#define RRL 8
#define BB 4
#define EE 800000
#define NT (RRL * NN)       // 400000 (rel,dst) buckets
#define SCAN_CHUNK 2048
#define NBLK_SCAN ((NT + SCAN_CHUNK - 1) / SCAN_CHUNK)  // 196

typedef short bf16x8_t __attribute__((ext_vector_type(8)));
typedef float f32x4_t __attribute__((ext_vector_type(4)));

__device__ __forceinline__ unsigned short f2bf(float f) {
  unsigned int x = __float_as_uint(f);
  unsigned int r = x + 0x7fffu + ((x >> 16) & 1u);
  return (unsigned short)(r >> 16);
}
__device__ __forceinline__ float bflo(unsigned int u) { return __uint_as_float(u << 16); }
__device__ __forceinline__ float bfhi(unsigned int u) {
  return __uint_as_float(u & 0xffff0000u);
}

// ---------------- utility ----------------

__global__ __launch_bounds__(256) void zero_kernel(int* p, int n) {
  int i = blockIdx.x * 256 + threadIdx.x;
  if (i < n) p[i] = 0;
}

// ---------------- counting sort by key = rel*NN + dst ----------------

__global__ __launch_bounds__(256) void hist2_kernel(const int* __restrict__ r,
                                                    const int* __restrict__ dst,
                                                    int* __restrict__ cnt) {
  int e = blockIdx.x * 256 + threadIdx.x;
  if (e < EE) atomicAdd(&cnt[r[e] * NN + dst[e]], 1);
}

__global__ __launch_bounds__(256) void scanA_kernel(const int* __restrict__ cnt,
                                                    int* __restrict__ off,
                                                    int* __restrict__ partials) {
  __shared__ int sums[256];
  int tid = threadIdx.x;
  int base = blockIdx.x * SCAN_CHUNK + tid * 8;
  int v[8];
  int s = 0;
#pragma unroll
  for (int j = 0; j < 8; ++j) {
    int idx = base + j;
    v[j] = (idx < NT) ? cnt[idx] : 0;
    s += v[j];
  }
  sums[tid] = s;
  __syncthreads();
  for (int o = 1; o < 256; o <<= 1) {
    int t = (tid >= o) ? sums[tid - o] : 0;
    __syncthreads();
    sums[tid] += t;
    __syncthreads();
  }
  int run = sums[tid] - s;
#pragma unroll
  for (int j = 0; j < 8; ++j) {
    int idx = base + j;
    if (idx < NT) off[idx] = run;
    run += v[j];
  }
  if (tid == 255) partials[blockIdx.x] = sums[255];
}

__global__ __launch_bounds__(256) void scanB_kernel(const int* __restrict__ partials,
                                                    int* __restrict__ pexcl) {
  __shared__ int sums[256];
  int tid = threadIdx.x;
  int p = (tid < NBLK_SCAN) ? partials[tid] : 0;
  sums[tid] = p;
  __syncthreads();
  for (int o = 1; o < 256; o <<= 1) {
    int t = (tid >= o) ? sums[tid - o] : 0;
    __syncthreads();
    sums[tid] += t;
    __syncthreads();
  }
  if (tid < NBLK_SCAN) pexcl[tid] = sums[tid] - p;
}

__global__ __launch_bounds__(256) void addC_kernel(int* __restrict__ off,
                                                   const int* __restrict__ pexcl,
                                                   int* __restrict__ cur) {
  int tid = threadIdx.x;
  int add = pexcl[blockIdx.x];
  int base = blockIdx.x * SCAN_CHUNK + tid * 8;
#pragma unroll
  for (int j = 0; j < 8; ++j) {
    int idx = base + j;
    if (idx < NT) {
      int v = off[idx] + add;
      off[idx] = v;
      cur[idx] = v;
    }
  }
  if (blockIdx.x == 0 && tid == 0) off[NT] = EE;
}

__global__ __launch_bounds__(256) void scatter2_kernel(
    const int* __restrict__ r, const int* __restrict__ dst, const int* __restrict__ src,
    const int* __restrict__ h, const float* __restrict__ norm, int* __restrict__ cur,
    int* __restrict__ src_s, int* __restrict__ hs_s, float* __restrict__ norm_s) {
  int e = blockIdx.x * 256 + threadIdx.x;
  if (e >= EE) return;
  int key = r[e] * NN + dst[e];
  int pos = atomicAdd(&cur[key], 1);
  int sv = src[e];
  src_s[pos] = sv;
  hs_s[pos] = h[sv];
  norm_s[pos] = norm[e];
}

// ---------------- compose small weights (bf16, transposed [n][k]) ----------------

__global__ __launch_bounds__(256) void compose_small_kernel(
    const float* __restrict__ wcomp1, const float* __restrict__ bases1,
    const float* __restrict__ loop1, const float* __restrict__ wcomp2,
    const float* __restrict__ bases2, const float* __restrict__ loop2,
    unsigned short* __restrict__ w1t, unsigned short* __restrict__ loop1t,
    unsigned short* __restrict__ w2t, unsigned short* __restrict__ loop2t) {
  int idx = blockIdx.x * 256 + threadIdx.x;
  if (idx < RRL * HH * HH) {  // w1t[z][n][k]
    int z = idx >> 14;
    int rem = idx & 16383;
    int n = rem >> 7, k = rem & 127;
    float a = 0.f;
#pragma unroll
    for (int b = 0; b < BB; ++b)
      a += wcomp1[z * BB + b] * bases1[((size_t)b * HH + k) * HH + n];
    w1t[idx] = f2bf(a);
    return;
  }
  int j = idx - RRL * HH * HH;
  if (j < HH * HH) {  // loop1t[n][k]
    int n = j >> 7, k = j & 127;
    loop1t[j] = f2bf(loop1[k * HH + n]);
    return;
  }
  j -= HH * HH;
  if (j < RRL * CC * HH) {  // w2t[z][n][k]
    int z = j >> 11;
    int rem = j & 2047;
    int n = rem >> 7, k = rem & 127;
    float a = 0.f;
#pragma unroll
    for (int b = 0; b < BB; ++b)
      a += wcomp2[z * BB + b] * bases2[((size_t)b * HH + k) * CC + n];
    w2t[j] = f2bf(a);
    return;
  }
  j -= RRL * CC * HH;
  if (j < CC * HH) {  // loop2t[n][k]
    int n = j >> 7, k = j & 127;
    loop2t[j] = f2bf(loop2[k * CC + n]);
  }
}

// ---------------- w0 bf16 table: w0b[z][m][f] = sum_b wcomp0[z,b]*bases0[b,m,f] ----------------

__global__ __launch_bounds__(256) void w0b_build_kernel(const float* __restrict__ bases0,
                                                        const float* __restrict__ wcomp0,
                                                        unsigned short* __restrict__ w0b) {
  int idx = blockIdx.x * 256 + threadIdx.x;  // m*32 + c (c = float4 chunk)
  int m = idx >> 5, c = idx & 31;
  if (m >= NN) return;
  float4 b0 = ((const float4*)(bases0 + ((size_t)0 * NN + m) * HH))[c];
  float4 b1 = ((const float4*)(bases0 + ((size_t)1 * NN + m) * HH))[c];
  float4 b2 = ((const float4*)(bases0 + ((size_t)2 * NN + m) * HH))[c];
  float4 b3 = ((const float4*)(bases0 + ((size_t)3 * NN + m) * HH))[c];
#pragma unroll
  for (int z = 0; z < RRL; ++z) {
    float c0 = wcomp0[z * BB + 0], c1 = wcomp0[z * BB + 1];
    float c2 = wcomp0[z * BB + 2], c3 = wcomp0[z * BB + 3];
    float vx = c0 * b0.x + c1 * b1.x + c2 * b2.x + c3 * b3.x;
    float vy = c0 * b0.y + c1 * b1.y + c2 * b2.y + c3 * b3.y;
    float vz = c0 * b0.z + c1 * b1.z + c2 * b2.z + c3 * b3.z;
    float vw = c0 * b0.w + c1 * b1.w + c2 * b2.w + c3 * b3.w;
    uint2 pk;
    pk.x = ((unsigned)f2bf(vy) << 16) | f2bf(vx);
    pk.y = ((unsigned)f2bf(vw) << 16) | f2bf(vz);
    ((uint2*)(w0b + ((size_t)z * NP + m) * HH))[c] = pk;
  }
}

// ---------------- layer 0: wave/dst, 4 edge-slots x 16 lanes, pipelined (big path) ----------------

__global__ __launch_bounds__(256) void l0_seg_big_kernel(
    const int* __restrict__ h, const int* __restrict__ off2, const int* __restrict__ hs_s,
    const float* __restrict__ norm_s, const unsigned short* __restrict__ w0b,
    const float* __restrict__ loop0, const float* __restrict__ bias0,
    unsigned short* __restrict__ x1b) {
  int lane = threadIdx.x & 63;
  int n = blockIdx.x * 4 + (threadIdx.x >> 6);
  if (n >= NP) return;
  const int g = lane >> 4;   // edge slot 0..3
  const int t = lane & 15;   // 16B chunk of 256B row
  float acc[8];
#pragma unroll
  for (int j = 0; j < 8; ++j) acc[j] = 0.f;

  if (n < NN) {
    for (int z = 0; z < RRL; ++z) {
      int beg = off2[z * NN + n];
      int end = off2[z * NN + n + 1];
      int i = beg + g;
      int s = 0;
      float nrm = 0.f;
      if (i < end) { s = hs_s[i]; nrm = norm_s[i]; }
      while (i < end) {
        int i2 = i + 4;
        int s2 = 0;
        float nrm2 = 0.f;
        if (i2 < end) { s2 = hs_s[i2]; nrm2 = norm_s[i2]; }
        uint4 v = *(const uint4*)(w0b + ((size_t)z * NP + s) * HH + t * 8);
        acc[0] = fmaf(nrm, bflo(v.x), acc[0]);
        acc[1] = fmaf(nrm, bfhi(v.x), acc[1]);
        acc[2] = fmaf(nrm, bflo(v.y), acc[2]);
        acc[3] = fmaf(nrm, bfhi(v.y), acc[3]);
        acc[4] = fmaf(nrm, bflo(v.z), acc[4]);
        acc[5] = fmaf(nrm, bfhi(v.z), acc[5]);
        acc[6] = fmaf(nrm, bflo(v.w), acc[6]);
        acc[7] = fmaf(nrm, bfhi(v.w), acc[7]);
        i = i2; s = s2; nrm = nrm2;
      }
    }
  }
  // reduce across the 4 edge-slot groups
#pragma unroll
  for (int j = 0; j < 8; ++j) {
    acc[j] += __shfl_xor(acc[j], 16, 64);
    acc[j] += __shfl_xor(acc[j], 32, 64);
  }
  if (g != 0) return;
  uint4 o = {0u, 0u, 0u, 0u};
  if (n < NN) {
    int hn = h[n];
    float4 l0v = ((const float4*)(loop0 + (size_t)hn * HH))[t * 2];
    float4 l1v = ((const float4*)(loop0 + (size_t)hn * HH))[t * 2 + 1];
    float4 b0v = ((const float4*)bias0)[t * 2];
    float4 b1v = ((const float4*)bias0)[t * 2 + 1];
    float e0 = fmaxf(acc[0] + l0v.x + b0v.x, 0.f);
    float e1 = fmaxf(acc[1] + l0v.y + b0v.y, 0.f);
    float e2 = fmaxf(acc[2] + l0v.z + b0v.z, 0.f);
    float e3 = fmaxf(acc[3] + l0v.w + b0v.w, 0.f);
    float e4 = fmaxf(acc[4] + l1v.x + b1v.x, 0.f);
    float e5 = fmaxf(acc[5] + l1v.y + b1v.y, 0.f);
    float e6 = fmaxf(acc[6] + l1v.z + b1v.z, 0.f);
    float e7 = fmaxf(acc[7] + l1v.w + b1v.w, 0.f);
    o.x = ((unsigned)f2bf(e1) << 16) | f2bf(e0);
    o.y = ((unsigned)f2bf(e3) << 16) | f2bf(e2);
    o.z = ((unsigned)f2bf(e5) << 16) | f2bf(e4);
    o.w = ((unsigned)f2bf(e7) << 16) | f2bf(e6);
  }
  *(uint4*)(x1b + (size_t)n * HH + t * 8) = o;
}

// ---------------- layer 0 fallback: fp32 bases0 gather (small path) ----------------

__global__ __launch_bounds__(256) void l0_seg_small_kernel(
    const int* __restrict__ h, const int* __restrict__ off2, const int* __restrict__ hs_s,
    const float* __restrict__ norm_s, const float* __restrict__ wcomp0,
    const float* __restrict__ bases0, const float* __restrict__ loop0,
    const float* __restrict__ bias0, unsigned short* __restrict__ x1b) {
  int lane = threadIdx.x & 63;
  int n = blockIdx.x * 4 + (threadIdx.x >> 6);
  if (n >= NP) return;
  unsigned int* orow = (unsigned int*)x1b + (size_t)n * 64 + lane;
  if (n >= NN) { *orow = 0u; return; }
  float ax = 0.f, ay = 0.f;
  for (int z = 0; z < RRL; ++z) {
    float c0 = wcomp0[z * BB + 0], c1 = wcomp0[z * BB + 1];
    float c2 = wcomp0[z * BB + 2], c3 = wcomp0[z * BB + 3];
    int beg = off2[z * NN + n];
    int end = off2[z * NN + n + 1];
    for (int i = beg; i < end; ++i) {
      int hs = hs_s[i];
      float nrm = norm_s[i];
      float2 v0 = ((const float2*)(bases0 + ((size_t)0 * NN + hs) * HH))[lane];
      float2 v1 = ((const float2*)(bases0 + ((size_t)1 * NN + hs) * HH))[lane];
      float2 v2 = ((const float2*)(bases0 + ((size_t)2 * NN + hs) * HH))[lane];
      float2 v3 = ((const float2*)(bases0 + ((size_t)3 * NN + hs) * HH))[lane];
      float gx = c0 * v0.x + c1 * v1.x + c2 * v2.x + c3 * v3.x;
      float gy = c0 * v0.y + c1 * v1.y + c2 * v2.y + c3 * v3.y;
      ax = fmaf(nrm, gx, ax);
      ay = fmaf(nrm, gy, ay);
    }
  }
  int hn = h[n];
  float2 lv = ((const float2*)(loop0 + (size_t)hn * HH))[lane];
  float2 bv = ((const float2*)bias0)[lane];
  float ox = fmaxf(ax + lv.x + bv.x, 0.f);
  float oy = fmaxf(ay + lv.y + bv.y, 0.f);
  *orow = ((unsigned)f2bf(oy) << 16) | f2bf(ox);
}

// ---------------- bf16 MFMA GEMM: C = A(bf16 [NP x128]) @ Bt(bf16 [F x 128])^T ----------------

template <int F>
__global__ __launch_bounds__(256) void gemm_mfma_kernel(
    const unsigned short* __restrict__ A, const unsigned short* __restrict__ Ball,
    unsigned short* __restrict__ outb, float* __restrict__ outf,
    const float* __restrict__ bias, int Mvalid) {
  constexpr int ROWS = (F == 128) ? 64 : 128;
  constexpr int CT = (F == 128) ? 4 : 1;
  constexpr int LP = 136;
  __shared__ unsigned short Alds[ROWS * LP];
  __shared__ unsigned short Blds[F * LP];
  const int z = blockIdx.y;
  const int row0 = blockIdx.x * ROWS;
  const int tid = threadIdx.x;
  const unsigned short* B = Ball + (size_t)z * 128 * F;

#pragma unroll
  for (int it = 0; it < ROWS * 16 / 256; ++it) {
    int flat = tid + it * 256;
    int row = flat >> 4, c8 = flat & 15;
    uint4 v = *(const uint4*)(A + ((size_t)(row0 + row)) * 128 + c8 * 8);
    *(uint4*)(&Alds[row * LP + c8 * 8]) = v;
  }
#pragma unroll
  for (int it = 0; it < F * 16 / 256; ++it) {
    int flat = tid + it * 256;
    int row = flat >> 4, c8 = flat & 15;
    uint4 v = *(const uint4*)(B + (size_t)row * 128 + c8 * 8);
    *(uint4*)(&Blds[row * LP + c8 * 8]) = v;
  }
  __syncthreads();

  const int w = tid >> 6, lane = tid & 63;
  const int quad = lane >> 4, l15 = lane & 15;
  const int rb = (F == 128) ? (w >> 1) * 32 : w * 32;
  const int cb = (F == 128) ? (w & 1) * 64 : 0;

  f32x4_t acc[2][CT];
#pragma unroll
  for (int rt = 0; rt < 2; ++rt)
#pragma unroll
    for (int ct = 0; ct < CT; ++ct) acc[rt][ct] = (f32x4_t){0.f, 0.f, 0.f, 0.f};

#pragma unroll
  for (int ks = 0; ks < 4; ++ks) {
    int ko = ks * 32 + quad * 8;
    bf16x8_t af[2], bfr[CT];
#pragma unroll
    for (int rt = 0; rt < 2; ++rt)
      af[rt] = *(const bf16x8_t*)(&Alds[(rb + rt * 16 + l15) * LP + ko]);
#pragma unroll
    for (int ct = 0; ct < CT; ++ct)
      bfr[ct] = *(const bf16x8_t*)(&Blds[(cb + ct * 16 + l15) * LP + ko]);
#pragma unroll
    for (int rt = 0; rt < 2; ++rt)
#pragma unroll
      for (int ct = 0; ct < CT; ++ct)
        acc[rt][ct] =
            __builtin_amdgcn_mfma_f32_16x16x32_bf16(af[rt], bfr[ct], acc[rt][ct], 0, 0, 0);
  }

  if (outf) {
#pragma unroll
    for (int rt = 0; rt < 2; ++rt)
#pragma unroll
      for (int ct = 0; ct < CT; ++ct) {
        int n = cb + ct * 16 + l15;
        float bv = bias[n];
#pragma unroll
        for (int i = 0; i < 4; ++i) {
          int m = row0 + rb + rt * 16 + quad * 4 + i;
          if (m < Mvalid) outf[(size_t)m * F + n] = acc[rt][ct][i] + bv;
        }
      }
  } else {
    unsigned short* ob = outb + (size_t)z * NP * F;
#pragma unroll
    for (int rt = 0; rt < 2; ++rt)
#pragma unroll
      for (int ct = 0; ct < CT; ++ct) {
        int n = cb + ct * 16 + l15;
#pragma unroll
        for (int i = 0; i < 4; ++i) {
          int m = row0 + rb + rt * 16 + quad * 4 + i;
          ob[(size_t)m * F + n] = f2bf(acc[rt][ct][i]);
        }
      }
  }
}

// ---------------- layer 1 gather (big): all rels, 4 edge-slots x 16 lanes, pipelined ----------------

__global__ __launch_bounds__(256) void l1_seg_merged_kernel(
    const int* __restrict__ off2, const int* __restrict__ src_s,
    const float* __restrict__ norm_s, const unsigned short* __restrict__ transb,
    const float* __restrict__ x2init, unsigned short* __restrict__ x2b) {
  int lane = threadIdx.x & 63;
  int n = blockIdx.x * 4 + (threadIdx.x >> 6);
  if (n >= NP) return;
  const int g = lane >> 4;
  const int t = lane & 15;
  float acc[8];
#pragma unroll
  for (int j = 0; j < 8; ++j) acc[j] = 0.f;

  if (n < NN) {
    for (int z = 0; z < RRL; ++z) {
      int beg = off2[z * NN + n];
      int end = off2[z * NN + n + 1];
      int i = beg + g;
      int s = 0;
      float nrm = 0.f;
      if (i < end) { s = src_s[i]; nrm = norm_s[i]; }
      while (i < end) {
        int i2 = i + 4;
        int s2 = 0;
        float nrm2 = 0.f;
        if (i2 < end) { s2 = src_s[i2]; nrm2 = norm_s[i2]; }
        uint4 v = *(const uint4*)(transb + ((size_t)z * NP + s) * HH + t * 8);
        acc[0] = fmaf(nrm, bflo(v.x), acc[0]);
        acc[1] = fmaf(nrm, bfhi(v.x), acc[1]);
        acc[2] = fmaf(nrm, bflo(v.y), acc[2]);
        acc[3] = fmaf(nrm, bfhi(v.y), acc[3]);
        acc[4] = fmaf(nrm, bflo(v.z), acc[4]);
        acc[5] = fmaf(nrm, bfhi(v.z), acc[5]);
        acc[6] = fmaf(nrm, bflo(v.w), acc[6]);
        acc[7] = fmaf(nrm, bfhi(v.w), acc[7]);
        i = i2; s = s2; nrm = nrm2;
      }
    }
  }
#pragma unroll
  for (int j = 0; j < 8; ++j) {
    acc[j] += __shfl_xor(acc[j], 16, 64);
    acc[j] += __shfl_xor(acc[j], 32, 64);
  }
  if (g != 0) return;
  float4 s0 = ((const float4*)(x2init + (size_t)n * HH))[t * 2];
  float4 s1 = ((const float4*)(x2init + (size_t)n * HH))[t * 2 + 1];
  float e0 = fmaxf(acc[0] + s0.x, 0.f);
  float e1 = fmaxf(acc[1] + s0.y, 0.f);
  float e2 = fmaxf(acc[2] + s0.z, 0.f);
  float e3 = fmaxf(acc[3] + s0.w, 0.f);
  float e4 = fmaxf(acc[4] + s1.x, 0.f);
  float e5 = fmaxf(acc[5] + s1.y, 0.f);
  float e6 = fmaxf(acc[6] + s1.z, 0.f);
  float e7 = fmaxf(acc[7] + s1.w, 0.f);
  uint4 o;
  o.x = ((unsigned)f2bf(e1) << 16) | f2bf(e0);
  o.y = ((unsigned)f2bf(e3) << 16) | f2bf(e2);
  o.z = ((unsigned)f2bf(e5) << 16) | f2bf(e4);
  o.w = ((unsigned)f2bf(e7) << 16) | f2bf(e6);
  *(uint4*)(x2b + (size_t)n * HH + t * 8) = o;
}

// ---------------- layer 1 gather (small): one rel, RMW into fp32 x2init ----------------

__global__ __launch_bounds__(256) void l1_seg_perrel_kernel(
    const int* __restrict__ off2, const int* __restrict__ src_s,
    const float* __restrict__ norm_s, int z, const unsigned short* __restrict__ transbuf,
    float* __restrict__ x2init) {
  int lane = threadIdx.x & 63;
  int n = blockIdx.x * 4 + (threadIdx.x >> 6);
  if (n >= NN) return;
  int beg = off2[z * NN + n];
  int end = off2[z * NN + n + 1];
  if (beg == end) return;
  float ax = 0.f, ay = 0.f;
  for (int i = beg; i < end; ++i) {
    int s = src_s[i];
    float nrm = norm_s[i];
    unsigned int u = *(const unsigned int*)(transbuf + (size_t)s * HH + lane * 2);
    ax = fmaf(nrm, bflo(u), ax);
    ay = fmaf(nrm, bfhi(u), ay);
  }
  float2* o = (float2*)(x2init + (size_t)n * HH) + lane;
  float2 cv = *o;
  cv.x += ax;
  cv.y += ay;
  *o = cv;
}

__global__ __launch_bounds__(256) void x2fin_kernel(const float* __restrict__ x2init,
                                                    unsigned short* __restrict__ x2b) {
  int idx = blockIdx.x * 256 + threadIdx.x;
  float2 v = ((const float2*)x2init)[idx];
  ((unsigned int*)x2b)[idx] =
      ((unsigned)f2bf(fmaxf(v.y, 0.f)) << 16) | f2bf(fmaxf(v.x, 0.f));
}

// ---------------- layer 2 gather: wave/dst, 8 edge-slots x 8 lanes, pipelined ----------------

__global__ __launch_bounds__(256) void l2_seg_kernel(
    const int* __restrict__ off2, const int* __restrict__ src_s,
    const float* __restrict__ norm_s, const unsigned short* __restrict__ trans2,
    float* __restrict__ outp) {
  int lane = threadIdx.x & 63;
  int n = blockIdx.x * 4 + (threadIdx.x >> 6);
  if (n >= NN) return;
  const int g = lane >> 3;  // edge slot 0..7
  const int t = lane & 7;   // 4B chunk of 32B row
  float a0 = 0.f, a1 = 0.f;
  for (int z = 0; z < RRL; ++z) {
    int beg = off2[z * NN + n];
    int end = off2[z * NN + n + 1];
    int i = beg + g;
    int s = 0;
    float nrm = 0.f;
    if (i < end) { s = src_s[i]; nrm = norm_s[i]; }
    while (i < end) {
      int i2 = i + 8;
      int s2 = 0;
      float nrm2 = 0.f;
      if (i2 < end) { s2 = src_s[i2]; nrm2 = norm_s[i2]; }
      unsigned int u = *(const unsigned int*)(trans2 + ((size_t)z * NP + s) * CC + t * 2);
      a0 = fmaf(nrm, bflo(u), a0);
      a1 = fmaf(nrm, bfhi(u), a1);
      i = i2; s = s2; nrm = nrm2;
    }
  }
  a0 += __shfl_xor(a0, 8, 64);
  a0 += __shfl_xor(a0, 16, 64);
  a0 += __shfl_xor(a0, 32, 64);
  a1 += __shfl_xor(a1, 8, 64);
  a1 += __shfl_xor(a1, 16, 64);
  a1 += __shfl_xor(a1, 32, 64);
  if (g != 0) return;
  float2* o = (float2*)(outp + (size_t)n * CC) + t;
  float2 cv = *o;
  cv.x += a0;
  cv.y += a1;
  *o = cv;
}

// ---------------- launch ----------------

extern "C" void kernel_launch(void* const* d_in, const int* in_sizes, int n_in,
                              void* d_out, int out_size, void* d_ws, size_t ws_size,
                              hipStream_t stream) {
  const int* src = (const int*)d_in[0];
  const int* dst = (const int*)d_in[1];
  const int* h = (const int*)d_in[2];
  const int* r = (const int*)d_in[3];
  const float* norm = (const float*)d_in[4];
  const float* bases0 = (const float*)d_in[5];
  const float* wcomp0 = (const float*)d_in[6];
  const float* loop0 = (const float*)d_in[7];
  const float* bias0 = (const float*)d_in[8];
  const float* bases1 = (const float*)d_in[9];
  const float* wcomp1 = (const float*)d_in[10];
  const float* loop1 = (const float*)d_in[11];
  const float* bias1 = (const float*)d_in[12];
  const float* bases2 = (const float*)d_in[13];
  const float* wcomp2 = (const float*)d_in[14];
  const float* loop2 = (const float*)d_in[15];
  const float* bias2 = (const float*)d_in[16];
  float* out = (float*)d_out;

  char* p = (char*)d_ws;
  auto alloc = [&](size_t bytes) {
    char* q = p;
    p += (bytes + 255) & ~(size_t)255;
    return q;
  };
  unsigned short* x1b = (unsigned short*)alloc((size_t)NP * HH * 2);
  unsigned short* x2b = (unsigned short*)alloc((size_t)NP * HH * 2);
  float* x2init = (float*)alloc((size_t)NP * HH * 4);
  unsigned short* trans2 = (unsigned short*)alloc((size_t)RRL * NP * CC * 2);
  unsigned short* w1t = (unsigned short*)alloc((size_t)RRL * HH * HH * 2);
  unsigned short* loop1t = (unsigned short*)alloc((size_t)HH * HH * 2);
  unsigned short* w2t = (unsigned short*)alloc((size_t)RRL * CC * HH * 2);
  unsigned short* loop2t = (unsigned short*)alloc((size_t)CC * HH * 2);
  float* norm_s = (float*)alloc((size_t)EE * 4);
  int* src_s = (int*)alloc((size_t)EE * 4);
  int* hs_s = (int*)alloc((size_t)EE * 4);
  int* off2 = (int*)alloc((size_t)(NT + 1) * 4);
  int* cur2 = (int*)alloc((size_t)NT * 4);
  int* cnt2 = (int*)alloc((size_t)NT * 4);
  int* partials = (int*)alloc(1024);
  int* pexcl = (int*)alloc(1024);
  unsigned short* BIG = (unsigned short*)p;  // w0b / trans_b (big) or per-rel transbuf (small)
  size_t used = (size_t)(p - (char*)d_ws);
  size_t big_bytes = (size_t)RRL * NP * HH * 2;  // 102.5 MB
  bool big = (used + big_bytes) <= ws_size;

  // ---- counting sort of edges by (rel, dst) ----
  zero_kernel<<<(NT + 255) / 256, 256, 0, stream>>>(cnt2, NT);
  hist2_kernel<<<(EE + 255) / 256, 256, 0, stream>>>(r, dst, cnt2);
  scanA_kernel<<<NBLK_SCAN, 256, 0, stream>>>(cnt2, off2, partials);
  scanB_kernel<<<1, 256, 0, stream>>>(partials, pexcl);
  addC_kernel<<<NBLK_SCAN, 256, 0, stream>>>(off2, pexcl, cur2);
  scatter2_kernel<<<(EE + 255) / 256, 256, 0, stream>>>(r, dst, src, h, norm, cur2, src_s,
                                                        hs_s, norm_s);

  // ---- compose bf16 weights (transposed [n][k]) ----
  compose_small_kernel<<<648, 256, 0, stream>>>(wcomp1, bases1, loop1, wcomp2, bases2, loop2,
                                                w1t, loop1t, w2t, loop2t);

  // ---- layer 0 ----
  if (big) {
    w0b_build_kernel<<<(NN * 32) / 256, 256, 0, stream>>>(bases0, wcomp0, BIG);
    l0_seg_big_kernel<<<NP / 4, 256, 0, stream>>>(h, off2, hs_s, norm_s, BIG, loop0, bias0,
                                                  x1b);
  } else {
    l0_seg_small_kernel<<<NP / 4, 256, 0, stream>>>(h, off2, hs_s, norm_s, wcomp0, bases0,
                                                    loop0, bias0, x1b);
  }

  // ---- layer 1 ----
  gemm_mfma_kernel<128><<<dim3(NP / 64, 1), 256, 0, stream>>>(x1b, loop1t, nullptr, x2init,
                                                              bias1, NP);
  if (big) {
    gemm_mfma_kernel<128><<<dim3(NP / 64, RRL), 256, 0, stream>>>(x1b, w1t, BIG, nullptr,
                                                                  nullptr, NP);
    l1_seg_merged_kernel<<<NP / 4, 256, 0, stream>>>(off2, src_s, norm_s, BIG, x2init, x2b);
  } else {
    for (int z = 0; z < RRL; ++z) {
      gemm_mfma_kernel<128><<<dim3(NP / 64, 1), 256, 0, stream>>>(
          x1b, w1t + (size_t)z * HH * HH, BIG, nullptr, nullptr, NP);
      l1_seg_perrel_kernel<<<NP / 4, 256, 0, stream>>>(off2, src_s, norm_s, z, BIG, x2init);
    }
    x2fin_kernel<<<NP * 64 / 256, 256, 0, stream>>>(x2init, x2b);
  }

  // ---- layer 2 ----
  gemm_mfma_kernel<16><<<dim3(NP / 128, RRL), 256, 0, stream>>>(x2b, w2t, trans2, nullptr,
                                                                nullptr, NP);
  gemm_mfma_kernel<16><<<dim3(NP / 128, 1), 256, 0, stream>>>(x2b, loop2t, nullptr, out,
                                                              bias2, NN);
  l2_seg_kernel<<<(NN + 3) / 4, 256, 0, stream>>>(off2, src_s, norm_s, trans2, out);
}

// Round 5
// 529.054 us; speedup vs baseline: 4.4808x; 1.1395x over previous
//
#include <hip/hip_runtime.h>

#define NN 50000
#define NP 50048            // padded rows (multiple of 128)
#define HH 128
#define CC 16
#define RRL 8
#define BB 4
#define EE 800000
#define NT (RRL * NN)       // 400000 (dst,rel) buckets, key = dst*8+rel
#define SCAN_CHUNK 2048
#define NBLK_SCAN ((NT + SCAN_CHUNK - 1) / SCAN_CHUNK)  // 196
#define KBIG 1152           // 8*128 (relations) + 128 (self-loop)

typedef short bf16x8_t __attribute__((ext_vector_type(8)));
typedef float f32x4_t __attribute__((ext_vector_type(4)));

__device__ __forceinline__ unsigned short f2bf(float f) {
  unsigned int x = __float_as_uint(f);
  unsigned int r = x + 0x7fffu + ((x >> 16) & 1u);
  return (unsigned short)(r >> 16);
}
__device__ __forceinline__ float bflo(unsigned int u) { return __uint_as_float(u << 16); }
__device__ __forceinline__ float bfhi(unsigned int u) {
  return __uint_as_float(u & 0xffff0000u);
}

// ---------------- utility ----------------

__global__ __launch_bounds__(256) void zero_kernel(int* p, int n) {
  int i = blockIdx.x * 256 + threadIdx.x;
  if (i < n) p[i] = 0;
}

// ---------------- counting sort by key = dst*8 + rel ----------------

__global__ __launch_bounds__(256) void hist2_kernel(const int* __restrict__ r,
                                                    const int* __restrict__ dst,
                                                    int* __restrict__ cnt) {
  int e = blockIdx.x * 256 + threadIdx.x;
  if (e < EE) atomicAdd(&cnt[dst[e] * RRL + r[e]], 1);
}

__global__ __launch_bounds__(256) void scanA_kernel(const int* __restrict__ cnt,
                                                    int* __restrict__ off,
                                                    int* __restrict__ partials) {
  __shared__ int sums[256];
  int tid = threadIdx.x;
  int base = blockIdx.x * SCAN_CHUNK + tid * 8;
  int v[8];
  int s = 0;
#pragma unroll
  for (int j = 0; j < 8; ++j) {
    int idx = base + j;
    v[j] = (idx < NT) ? cnt[idx] : 0;
    s += v[j];
  }
  sums[tid] = s;
  __syncthreads();
  for (int o = 1; o < 256; o <<= 1) {
    int t = (tid >= o) ? sums[tid - o] : 0;
    __syncthreads();
    sums[tid] += t;
    __syncthreads();
  }
  int run = sums[tid] - s;
#pragma unroll
  for (int j = 0; j < 8; ++j) {
    int idx = base + j;
    if (idx < NT) off[idx] = run;
    run += v[j];
  }
  if (tid == 255) partials[blockIdx.x] = sums[255];
}

__global__ __launch_bounds__(256) void scanB_kernel(const int* __restrict__ partials,
                                                    int* __restrict__ pexcl) {
  __shared__ int sums[256];
  int tid = threadIdx.x;
  int p = (tid < NBLK_SCAN) ? partials[tid] : 0;
  sums[tid] = p;
  __syncthreads();
  for (int o = 1; o < 256; o <<= 1) {
    int t = (tid >= o) ? sums[tid - o] : 0;
    __syncthreads();
    sums[tid] += t;
    __syncthreads();
  }
  if (tid < NBLK_SCAN) pexcl[tid] = sums[tid] - p;
}

__global__ __launch_bounds__(256) void addC_kernel(int* __restrict__ off,
                                                   const int* __restrict__ pexcl,
                                                   int* __restrict__ cur) {
  int tid = threadIdx.x;
  int add = pexcl[blockIdx.x];
  int base = blockIdx.x * SCAN_CHUNK + tid * 8;
#pragma unroll
  for (int j = 0; j < 8; ++j) {
    int idx = base + j;
    if (idx < NT) {
      int v = off[idx] + add;
      off[idx] = v;
      cur[idx] = v;
    }
  }
  if (blockIdx.x == 0 && tid == 0) off[NT] = EE;
}

// payloads: ep0 = (w0b row index = z*NP + h[src], norm bits)
//           ep1 = (src | z<<24, norm bits)
__global__ __launch_bounds__(256) void scatter2_kernel(
    const int* __restrict__ r, const int* __restrict__ dst, const int* __restrict__ src,
    const int* __restrict__ h, const float* __restrict__ norm, int* __restrict__ cur,
    uint2* __restrict__ ep0, uint2* __restrict__ ep1) {
  int e = blockIdx.x * 256 + threadIdx.x;
  if (e >= EE) return;
  int z = r[e];
  int key = dst[e] * RRL + z;
  int pos = atomicAdd(&cur[key], 1);
  int sv = src[e];
  unsigned int nb = __float_as_uint(norm[e]);
  uint2 a, b;
  a.x = (unsigned)(z * NP + h[sv]);
  a.y = nb;
  b.x = (unsigned)sv | ((unsigned)z << 24);
  b.y = nb;
  ep0[pos] = a;
  ep1[pos] = b;
}

// ---------------- compose weights (bf16) ----------------
// w1big[n][k], k in [0,1024): rel z=k>>7; k in [1024,1152): loop1. Layout row-major [128][1152].
// w2t[z][n16][k128], loop2t[n16][k128].

__global__ __launch_bounds__(256) void compose_small_kernel(
    const float* __restrict__ wcomp1, const float* __restrict__ bases1,
    const float* __restrict__ loop1, const float* __restrict__ wcomp2,
    const float* __restrict__ bases2, const float* __restrict__ loop2,
    unsigned short* __restrict__ w1big, unsigned short* __restrict__ w2t,
    unsigned short* __restrict__ loop2t) {
  int idx = blockIdx.x * 256 + threadIdx.x;
  if (idx < HH * KBIG) {  // w1big[n][k]
    int n = idx / KBIG, k = idx - n * KBIG;
    float a;
    if (k < 1024) {
      int z = k >> 7, kk = k & 127;
      a = 0.f;
#pragma unroll
      for (int b = 0; b < BB; ++b)
        a += wcomp1[z * BB + b] * bases1[((size_t)b * HH + kk) * HH + n];
    } else {
      int kk = k - 1024;
      a = loop1[kk * HH + n];
    }
    w1big[idx] = f2bf(a);
    return;
  }
  int j = idx - HH * KBIG;
  if (j < RRL * CC * HH) {  // w2t[z][n][k]
    int z = j >> 11;
    int rem = j & 2047;
    int n = rem >> 7, k = rem & 127;
    float a = 0.f;
#pragma unroll
    for (int b = 0; b < BB; ++b)
      a += wcomp2[z * BB + b] * bases2[((size_t)b * HH + k) * CC + n];
    w2t[j] = f2bf(a);
    return;
  }
  j -= RRL * CC * HH;
  if (j < CC * HH) {  // loop2t[n][k]
    int n = j >> 7, k = j & 127;
    loop2t[j] = f2bf(loop2[k * CC + n]);
  }
}

// ---------------- w0 bf16 table: w0b[z][m][f] ----------------

__global__ __launch_bounds__(256) void w0b_build_kernel(const float* __restrict__ bases0,
                                                        const float* __restrict__ wcomp0,
                                                        unsigned short* __restrict__ w0b) {
  int idx = blockIdx.x * 256 + threadIdx.x;  // m*32 + c
  int m = idx >> 5, c = idx & 31;
  if (m >= NN) return;
  float4 b0 = ((const float4*)(bases0 + ((size_t)0 * NN + m) * HH))[c];
  float4 b1 = ((const float4*)(bases0 + ((size_t)1 * NN + m) * HH))[c];
  float4 b2 = ((const float4*)(bases0 + ((size_t)2 * NN + m) * HH))[c];
  float4 b3 = ((const float4*)(bases0 + ((size_t)3 * NN + m) * HH))[c];
#pragma unroll
  for (int z = 0; z < RRL; ++z) {
    float c0 = wcomp0[z * BB + 0], c1 = wcomp0[z * BB + 1];
    float c2 = wcomp0[z * BB + 2], c3 = wcomp0[z * BB + 3];
    float vx = c0 * b0.x + c1 * b1.x + c2 * b2.x + c3 * b3.x;
    float vy = c0 * b0.y + c1 * b1.y + c2 * b2.y + c3 * b3.y;
    float vz = c0 * b0.z + c1 * b1.z + c2 * b2.z + c3 * b3.z;
    float vw = c0 * b0.w + c1 * b1.w + c2 * b2.w + c3 * b3.w;
    uint2 pk;
    pk.x = ((unsigned)f2bf(vy) << 16) | f2bf(vx);
    pk.y = ((unsigned)f2bf(vw) << 16) | f2bf(vz);
    ((uint2*)(w0b + ((size_t)z * NP + m) * HH))[c] = pk;
  }
}

// ---------------- layer 0: wave/dst, merged range, 4 slots x 16 lanes, 2x unroll ----------------

__global__ __launch_bounds__(256) void l0_seg_kernel(
    const int* __restrict__ h, const int* __restrict__ off2, const uint2* __restrict__ ep0,
    const unsigned short* __restrict__ w0b, const float* __restrict__ loop0,
    const float* __restrict__ bias0, unsigned short* __restrict__ x1b) {
  int lane = threadIdx.x & 63;
  int n = blockIdx.x * 4 + (threadIdx.x >> 6);
  if (n >= NP) return;
  const int g = lane >> 4;
  const int t = lane & 15;
  float acc[8];
#pragma unroll
  for (int j = 0; j < 8; ++j) acc[j] = 0.f;

  if (n < NN) {
    int beg = off2[n * RRL];
    int end = off2[n * RRL + RRL];
    int i = beg + g;
    uint2 p0 = {0u, 0u}, p1 = {0u, 0u};
    if (i < end) p0 = ep0[i];
    if (i + 4 < end) p1 = ep0[i + 4];
    while (i < end) {
      uint2 q0 = {0u, 0u}, q1 = {0u, 0u};
      if (i + 8 < end) q0 = ep0[i + 8];
      if (i + 12 < end) q1 = ep0[i + 12];
      uint4 va = *(const uint4*)(w0b + (size_t)p0.x * HH + t * 8);
      uint4 vb = *(const uint4*)(w0b + (size_t)p1.x * HH + t * 8);
      float na = __uint_as_float(p0.y), nb = __uint_as_float(p1.y);
      acc[0] = fmaf(na, bflo(va.x), acc[0]);
      acc[1] = fmaf(na, bfhi(va.x), acc[1]);
      acc[2] = fmaf(na, bflo(va.y), acc[2]);
      acc[3] = fmaf(na, bfhi(va.y), acc[3]);
      acc[4] = fmaf(na, bflo(va.z), acc[4]);
      acc[5] = fmaf(na, bfhi(va.z), acc[5]);
      acc[6] = fmaf(na, bflo(va.w), acc[6]);
      acc[7] = fmaf(na, bfhi(va.w), acc[7]);
      acc[0] = fmaf(nb, bflo(vb.x), acc[0]);
      acc[1] = fmaf(nb, bfhi(vb.x), acc[1]);
      acc[2] = fmaf(nb, bflo(vb.y), acc[2]);
      acc[3] = fmaf(nb, bfhi(vb.y), acc[3]);
      acc[4] = fmaf(nb, bflo(vb.z), acc[4]);
      acc[5] = fmaf(nb, bfhi(vb.z), acc[5]);
      acc[6] = fmaf(nb, bflo(vb.w), acc[6]);
      acc[7] = fmaf(nb, bfhi(vb.w), acc[7]);
      i += 8;
      p0 = q0;
      p1 = q1;
    }
  }
#pragma unroll
  for (int j = 0; j < 8; ++j) {
    acc[j] += __shfl_xor(acc[j], 16, 64);
    acc[j] += __shfl_xor(acc[j], 32, 64);
  }
  if (g != 0) return;
  uint4 o = {0u, 0u, 0u, 0u};
  if (n < NN) {
    int hn = h[n];
    float4 l0v = ((const float4*)(loop0 + (size_t)hn * HH))[t * 2];
    float4 l1v = ((const float4*)(loop0 + (size_t)hn * HH))[t * 2 + 1];
    float4 b0v = ((const float4*)bias0)[t * 2];
    float4 b1v = ((const float4*)bias0)[t * 2 + 1];
    float e0 = fmaxf(acc[0] + l0v.x + b0v.x, 0.f);
    float e1 = fmaxf(acc[1] + l0v.y + b0v.y, 0.f);
    float e2 = fmaxf(acc[2] + l0v.z + b0v.z, 0.f);
    float e3 = fmaxf(acc[3] + l0v.w + b0v.w, 0.f);
    float e4 = fmaxf(acc[4] + l1v.x + b1v.x, 0.f);
    float e5 = fmaxf(acc[5] + l1v.y + b1v.y, 0.f);
    float e6 = fmaxf(acc[6] + l1v.z + b1v.z, 0.f);
    float e7 = fmaxf(acc[7] + l1v.w + b1v.w, 0.f);
    o.x = ((unsigned)f2bf(e1) << 16) | f2bf(e0);
    o.y = ((unsigned)f2bf(e3) << 16) | f2bf(e2);
    o.z = ((unsigned)f2bf(e5) << 16) | f2bf(e4);
    o.w = ((unsigned)f2bf(e7) << 16) | f2bf(e6);
  }
  *(uint4*)(x1b + (size_t)n * HH + t * 8) = o;
}

// ---------------- layer 1 aggregate: AGG[n][z*128+f] = sum_seg norm * x1b[src] ----------------

__global__ __launch_bounds__(256) void l1_agg_kernel(const int* __restrict__ off2,
                                                     const uint2* __restrict__ ep1,
                                                     const unsigned short* __restrict__ x1b,
                                                     unsigned short* __restrict__ AGG) {
  int lane = threadIdx.x & 63;
  int n = blockIdx.x * 4 + (threadIdx.x >> 6);
  if (n >= NP) return;
  unsigned short* arow = AGG + (size_t)n * 1024;
  if (n >= NN) {  // zero pad rows
    uint4 zz = {0u, 0u, 0u, 0u};
    ((uint4*)arow)[lane] = zz;
    ((uint4*)arow)[lane + 64] = zz;
    return;
  }
  const int g = lane >> 4;
  const int t = lane & 15;
  int base8 = n * RRL;
  for (int z = 0; z < RRL; ++z) {
    int beg = off2[base8 + z];
    int end = off2[base8 + z + 1];
    float acc[8];
#pragma unroll
    for (int j = 0; j < 8; ++j) acc[j] = 0.f;
    int i = beg + g;
    uint2 p0 = {0u, 0u}, p1 = {0u, 0u};
    if (i < end) p0 = ep1[i];
    if (i + 4 < end) p1 = ep1[i + 4];
    while (i < end) {
      uint2 q0 = {0u, 0u}, q1 = {0u, 0u};
      if (i + 8 < end) q0 = ep1[i + 8];
      if (i + 12 < end) q1 = ep1[i + 12];
      int s0 = p0.x & 0xFFFFFF, s1 = p1.x & 0xFFFFFF;
      uint4 va = *(const uint4*)(x1b + (size_t)s0 * HH + t * 8);
      uint4 vb = *(const uint4*)(x1b + (size_t)s1 * HH + t * 8);
      float na = __uint_as_float(p0.y), nb = __uint_as_float(p1.y);
      acc[0] = fmaf(na, bflo(va.x), acc[0]);
      acc[1] = fmaf(na, bfhi(va.x), acc[1]);
      acc[2] = fmaf(na, bflo(va.y), acc[2]);
      acc[3] = fmaf(na, bfhi(va.y), acc[3]);
      acc[4] = fmaf(na, bflo(va.z), acc[4]);
      acc[5] = fmaf(na, bfhi(va.z), acc[5]);
      acc[6] = fmaf(na, bflo(va.w), acc[6]);
      acc[7] = fmaf(na, bfhi(va.w), acc[7]);
      acc[0] = fmaf(nb, bflo(vb.x), acc[0]);
      acc[1] = fmaf(nb, bfhi(vb.x), acc[1]);
      acc[2] = fmaf(nb, bflo(vb.y), acc[2]);
      acc[3] = fmaf(nb, bfhi(vb.y), acc[3]);
      acc[4] = fmaf(nb, bflo(vb.z), acc[4]);
      acc[5] = fmaf(nb, bfhi(vb.z), acc[5]);
      acc[6] = fmaf(nb, bflo(vb.w), acc[6]);
      acc[7] = fmaf(nb, bfhi(vb.w), acc[7]);
      i += 8;
      p0 = q0;
      p1 = q1;
    }
#pragma unroll
    for (int j = 0; j < 8; ++j) {
      acc[j] += __shfl_xor(acc[j], 16, 64);
      acc[j] += __shfl_xor(acc[j], 32, 64);
    }
    if (g == 0) {
      uint4 o;
      o.x = ((unsigned)f2bf(acc[1]) << 16) | f2bf(acc[0]);
      o.y = ((unsigned)f2bf(acc[3]) << 16) | f2bf(acc[2]);
      o.z = ((unsigned)f2bf(acc[5]) << 16) | f2bf(acc[4]);
      o.w = ((unsigned)f2bf(acc[7]) << 16) | f2bf(acc[6]);
      *(uint4*)(arow + z * 128 + t * 8) = o;
    }
  }
}

// ---------------- K=1152 MFMA GEMM: x2b = relu([AGG | x1b] @ w1big^T + bias1) ----------------

__global__ __launch_bounds__(256) void gemm_k1152_kernel(
    const unsigned short* __restrict__ AGG, const unsigned short* __restrict__ x1b,
    const unsigned short* __restrict__ w1big, const float* __restrict__ bias1,
    unsigned short* __restrict__ x2b) {
  constexpr int LP = 136;
  __shared__ unsigned short Alds[64 * LP];
  __shared__ unsigned short Blds[128 * LP];
  const int row0 = blockIdx.x * 64;
  const int tid = threadIdx.x;
  const int w = tid >> 6, lane = tid & 63;
  const int quad = lane >> 4, l15 = lane & 15;
  const int rb = (w >> 1) * 32;
  const int cb = (w & 1) * 64;

  f32x4_t acc[2][4];
#pragma unroll
  for (int rt = 0; rt < 2; ++rt)
#pragma unroll
    for (int ct = 0; ct < 4; ++ct) acc[rt][ct] = (f32x4_t){0.f, 0.f, 0.f, 0.f};

  for (int kb = 0; kb < 9; ++kb) {
    if (kb) __syncthreads();
    // A tile 64 rows x 128 k
#pragma unroll
    for (int it = 0; it < 4; ++it) {
      int flat = tid + it * 256;
      int row = flat >> 4, c8 = flat & 15;
      const unsigned short* srcp =
          (kb < 8) ? AGG + (size_t)(row0 + row) * 1024 + kb * 128 + c8 * 8
                   : x1b + (size_t)(row0 + row) * 128 + c8 * 8;
      *(uint4*)(&Alds[row * LP + c8 * 8]) = *(const uint4*)srcp;
    }
    // B tile 128 n x 128 k
#pragma unroll
    for (int it = 0; it < 8; ++it) {
      int flat = tid + it * 256;
      int row = flat >> 4, c8 = flat & 15;
      *(uint4*)(&Blds[row * LP + c8 * 8]) =
          *(const uint4*)(w1big + (size_t)row * KBIG + kb * 128 + c8 * 8);
    }
    __syncthreads();
#pragma unroll
    for (int ks = 0; ks < 4; ++ks) {
      int ko = ks * 32 + quad * 8;
      bf16x8_t af[2], bfr[4];
#pragma unroll
      for (int rt = 0; rt < 2; ++rt)
        af[rt] = *(const bf16x8_t*)(&Alds[(rb + rt * 16 + l15) * LP + ko]);
#pragma unroll
      for (int ct = 0; ct < 4; ++ct)
        bfr[ct] = *(const bf16x8_t*)(&Blds[(cb + ct * 16 + l15) * LP + ko]);
#pragma unroll
      for (int rt = 0; rt < 2; ++rt)
#pragma unroll
        for (int ct = 0; ct < 4; ++ct)
          acc[rt][ct] =
              __builtin_amdgcn_mfma_f32_16x16x32_bf16(af[rt], bfr[ct], acc[rt][ct], 0, 0, 0);
    }
  }
#pragma unroll
  for (int rt = 0; rt < 2; ++rt)
#pragma unroll
    for (int ct = 0; ct < 4; ++ct) {
      int n = cb + ct * 16 + l15;
      float bv = bias1[n];
#pragma unroll
      for (int i = 0; i < 4; ++i) {
        int m = row0 + rb + rt * 16 + quad * 4 + i;
        float val = (m < NN) ? fmaxf(acc[rt][ct][i] + bv, 0.f) : 0.f;
        x2b[(size_t)m * HH + n] = f2bf(val);
      }
    }
}

// ---------------- layer-2 small MFMA GEMM (F=16): trans2 / out ----------------

__global__ __launch_bounds__(256) void gemm16_kernel(const unsigned short* __restrict__ A,
                                                     const unsigned short* __restrict__ Ball,
                                                     unsigned short* __restrict__ outb,
                                                     float* __restrict__ outf,
                                                     const float* __restrict__ bias,
                                                     int Mvalid) {
  constexpr int LP = 136;
  __shared__ unsigned short Alds[128 * LP];
  __shared__ unsigned short Blds[16 * LP];
  const int z = blockIdx.y;
  const int row0 = blockIdx.x * 128;
  const int tid = threadIdx.x;
  const unsigned short* B = Ball + (size_t)z * 128 * CC;

#pragma unroll
  for (int it = 0; it < 8; ++it) {
    int flat = tid + it * 256;
    int row = flat >> 4, c8 = flat & 15;
    *(uint4*)(&Alds[row * LP + c8 * 8]) =
        *(const uint4*)(A + ((size_t)(row0 + row)) * 128 + c8 * 8);
  }
  {
    int flat = tid;
    int row = flat >> 4, c8 = flat & 15;
    *(uint4*)(&Blds[row * LP + c8 * 8]) = *(const uint4*)(B + (size_t)row * 128 + c8 * 8);
  }
  __syncthreads();

  const int w = tid >> 6, lane = tid & 63;
  const int quad = lane >> 4, l15 = lane & 15;
  const int rb = w * 32;

  f32x4_t acc[2];
  acc[0] = (f32x4_t){0.f, 0.f, 0.f, 0.f};
  acc[1] = (f32x4_t){0.f, 0.f, 0.f, 0.f};
#pragma unroll
  for (int ks = 0; ks < 4; ++ks) {
    int ko = ks * 32 + quad * 8;
    bf16x8_t af[2], bfr;
    af[0] = *(const bf16x8_t*)(&Alds[(rb + l15) * LP + ko]);
    af[1] = *(const bf16x8_t*)(&Alds[(rb + 16 + l15) * LP + ko]);
    bfr = *(const bf16x8_t*)(&Blds[l15 * LP + ko]);
    acc[0] = __builtin_amdgcn_mfma_f32_16x16x32_bf16(af[0], bfr, acc[0], 0, 0, 0);
    acc[1] = __builtin_amdgcn_mfma_f32_16x16x32_bf16(af[1], bfr, acc[1], 0, 0, 0);
  }
  if (outf) {
#pragma unroll
    for (int rt = 0; rt < 2; ++rt) {
      float bv = bias[l15];
#pragma unroll
      for (int i = 0; i < 4; ++i) {
        int m = row0 + rb + rt * 16 + quad * 4 + i;
        if (m < Mvalid) outf[(size_t)m * CC + l15] = acc[rt][i] + bv;
      }
    }
  } else {
    unsigned short* ob = outb + (size_t)z * NP * CC;
#pragma unroll
    for (int rt = 0; rt < 2; ++rt)
#pragma unroll
      for (int i = 0; i < 4; ++i) {
        int m = row0 + rb + rt * 16 + quad * 4 + i;
        ob[(size_t)m * CC + l15] = f2bf(acc[rt][i]);
      }
  }
}

// ---------------- layer 2 gather: wave/dst, merged range, 8 slots x 8 lanes, 2x unroll ----------------

__global__ __launch_bounds__(256) void l2_seg_kernel(const int* __restrict__ off2,
                                                     const uint2* __restrict__ ep1,
                                                     const unsigned short* __restrict__ trans2,
                                                     float* __restrict__ outp) {
  int lane = threadIdx.x & 63;
  int n = blockIdx.x * 4 + (threadIdx.x >> 6);
  if (n >= NN) return;
  const int g = lane >> 3;
  const int t = lane & 7;
  float a0 = 0.f, a1 = 0.f;
  int beg = off2[n * RRL];
  int end = off2[n * RRL + RRL];
  int i = beg + g;
  uint2 p0 = {0u, 0u}, p1 = {0u, 0u};
  if (i < end) p0 = ep1[i];
  if (i + 8 < end) p1 = ep1[i + 8];
  while (i < end) {
    uint2 q0 = {0u, 0u}, q1 = {0u, 0u};
    if (i + 16 < end) q0 = ep1[i + 16];
    if (i + 24 < end) q1 = ep1[i + 24];
    unsigned s0 = p0.x & 0xFFFFFFu, z0 = p0.x >> 24;
    unsigned s1 = p1.x & 0xFFFFFFu, z1 = p1.x >> 24;
    unsigned int u0 =
        *(const unsigned int*)(trans2 + ((size_t)z0 * NP + s0) * CC + t * 2);
    unsigned int u1 =
        *(const unsigned int*)(trans2 + ((size_t)z1 * NP + s1) * CC + t * 2);
    float na = __uint_as_float(p0.y), nb = __uint_as_float(p1.y);
    a0 = fmaf(na, bflo(u0), a0);
    a1 = fmaf(na, bfhi(u0), a1);
    a0 = fmaf(nb, bflo(u1), a0);
    a1 = fmaf(nb, bfhi(u1), a1);
    i += 16;
    p0 = q0;
    p1 = q1;
  }
  a0 += __shfl_xor(a0, 8, 64);
  a0 += __shfl_xor(a0, 16, 64);
  a0 += __shfl_xor(a0, 32, 64);
  a1 += __shfl_xor(a1, 8, 64);
  a1 += __shfl_xor(a1, 16, 64);
  a1 += __shfl_xor(a1, 32, 64);
  if (g != 0) return;
  float2* o = (float2*)(outp + (size_t)n * CC) + t;
  float2 cv = *o;
  cv.x += a0;
  cv.y += a1;
  *o = cv;
}

// ---------------- launch ----------------

extern "C" void kernel_launch(void* const* d_in, const int* in_sizes, int n_in,
                              void* d_out, int out_size, void* d_ws, size_t ws_size,
                              hipStream_t stream) {
  const int* src = (const int*)d_in[0];
  const int* dst = (const int*)d_in[1];
  const int* h = (const int*)d_in[2];
  const int* r = (const int*)d_in[3];
  const float* norm = (const float*)d_in[4];
  const float* bases0 = (const float*)d_in[5];
  const float* wcomp0 = (const float*)d_in[6];
  const float* loop0 = (const float*)d_in[7];
  const float* bias0 = (const float*)d_in[8];
  const float* bases1 = (const float*)d_in[9];
  const float* wcomp1 = (const float*)d_in[10];
  const float* loop1 = (const float*)d_in[11];
  const float* bias1 = (const float*)d_in[12];
  const float* bases2 = (const float*)d_in[13];
  const float* wcomp2 = (const float*)d_in[14];
  const float* loop2 = (const float*)d_in[15];
  const float* bias2 = (const float*)d_in[16];
  float* out = (float*)d_out;

  char* p = (char*)d_ws;
  auto alloc = [&](size_t bytes) {
    char* q = p;
    p += (bytes + 255) & ~(size_t)255;
    return q;
  };
  unsigned short* x1b = (unsigned short*)alloc((size_t)NP * HH * 2);
  unsigned short* x2b = (unsigned short*)alloc((size_t)NP * HH * 2);
  unsigned short* trans2 = (unsigned short*)alloc((size_t)RRL * NP * CC * 2);
  unsigned short* w1big = (unsigned short*)alloc((size_t)HH * KBIG * 2);
  unsigned short* w2t = (unsigned short*)alloc((size_t)RRL * CC * HH * 2);
  unsigned short* loop2t = (unsigned short*)alloc((size_t)CC * HH * 2);
  uint2* ep0 = (uint2*)alloc((size_t)EE * 8);
  uint2* ep1 = (uint2*)alloc((size_t)EE * 8);
  int* off2 = (int*)alloc((size_t)(NT + 1) * 4);
  int* cur2 = (int*)alloc((size_t)NT * 4);
  int* cnt2 = (int*)alloc((size_t)NT * 4);
  int* partials = (int*)alloc(1024);
  int* pexcl = (int*)alloc(1024);
  // BIG: w0b [R][NP][128] bf16 during layer 0, then reused as AGG [NP][1024] bf16
  unsigned short* BIG = (unsigned short*)alloc((size_t)RRL * NP * HH * 2);

  // ---- counting sort of edges by (dst, rel) ----
  zero_kernel<<<(NT + 255) / 256, 256, 0, stream>>>(cnt2, NT);
  hist2_kernel<<<(EE + 255) / 256, 256, 0, stream>>>(r, dst, cnt2);
  scanA_kernel<<<NBLK_SCAN, 256, 0, stream>>>(cnt2, off2, partials);
  scanB_kernel<<<1, 256, 0, stream>>>(partials, pexcl);
  addC_kernel<<<NBLK_SCAN, 256, 0, stream>>>(off2, pexcl, cur2);
  scatter2_kernel<<<(EE + 255) / 256, 256, 0, stream>>>(r, dst, src, h, norm, cur2, ep0, ep1);

  // ---- compose bf16 weights ----
  compose_small_kernel<<<(HH * KBIG + RRL * CC * HH + CC * HH) / 256, 256, 0, stream>>>(
      wcomp1, bases1, loop1, wcomp2, bases2, loop2, w1big, w2t, loop2t);

  // ---- layer 0 ----
  w0b_build_kernel<<<(NN * 32) / 256, 256, 0, stream>>>(bases0, wcomp0, BIG);
  l0_seg_kernel<<<NP / 4, 256, 0, stream>>>(h, off2, ep0, BIG, loop0, bias0, x1b);

  // ---- layer 1: aggregate-then-transform (AGG overwrites w0b) ----
  l1_agg_kernel<<<NP / 4, 256, 0, stream>>>(off2, ep1, x1b, BIG);
  gemm_k1152_kernel<<<NP / 64, 256, 0, stream>>>(BIG, x1b, w1big, bias1, x2b);

  // ---- layer 2 ----
  gemm16_kernel<<<dim3(NP / 128, RRL), 256, 0, stream>>>(x2b, w2t, trans2, nullptr, nullptr,
                                                         NP);
  gemm16_kernel<<<dim3(NP / 128, 1), 256, 0, stream>>>(x2b, loop2t, nullptr, out, bias2, NN);
  l2_seg_kernel<<<(NN + 3) / 4, 256, 0, stream>>>(off2, ep1, trans2, out);
}